// Round 8
// baseline (817.066 us; speedup 1.0000x reference)
//
#include <hip/hip_runtime.h>
#include <cstdint>

typedef __bf16 bf16;
typedef float f32x4 __attribute__((ext_vector_type(4)));
typedef _Float16 fp16;
typedef _Float16 half8 __attribute__((ext_vector_type(8)));
typedef _Float16 half4 __attribute__((ext_vector_type(4)));

#define NEG_SLOPE 0.2f
#define BN_EPS 1e-5f

// ---------------- async global->LDS (16B per lane, wave-uniform LDS base) ----------------
__device__ __forceinline__ void gld_lds16(const void* g, void* l) {
  auto gp = reinterpret_cast<const __attribute__((address_space(1))) unsigned int*>(
      reinterpret_cast<uintptr_t>(g));
  auto lp = reinterpret_cast<__attribute__((address_space(3))) unsigned int*>(
      reinterpret_cast<uintptr_t>(l));
  __builtin_amdgcn_global_load_lds(gp, lp, 16, 0, 0);
}

// ---------------- CSR build ----------------
__global__ void k_init_counts(int* counts, int N) {
  int i = blockIdx.x * 256 + threadIdx.x;
  if (i < N) counts[i] = 1;  // self-loop
}

__global__ void k_count(const int* __restrict__ ei, int* counts, int E) {
  int i = blockIdx.x * 256 + threadIdx.x;
  if (i < E) atomicAdd(&counts[ei[E + i]], 1);
}

// phase 1: each block scans 1024 counts; writes local exclusive prefix into row_start,
// block total into bsums[blockIdx]
__global__ __launch_bounds__(256) void k_scan1(const int* __restrict__ counts,
                                               int* __restrict__ row_start,
                                               int* __restrict__ bsums, int N) {
  __shared__ int s[256];
  const int t = threadIdx.x;
  const int idx = blockIdx.x * 1024 + t * 4;
  int a0 = (idx + 0 < N) ? counts[idx + 0] : 0;
  int a1 = (idx + 1 < N) ? counts[idx + 1] : 0;
  int a2 = (idx + 2 < N) ? counts[idx + 2] : 0;
  int a3 = (idx + 3 < N) ? counts[idx + 3] : 0;
  const int mysum = a0 + a1 + a2 + a3;
  s[t] = mysum;
  __syncthreads();
  for (int ofs = 1; ofs < 256; ofs <<= 1) {
    int v = (t >= ofs) ? s[t - ofs] : 0;
    __syncthreads();
    s[t] += v;
    __syncthreads();
  }
  int excl = s[t] - mysum;
  if (idx + 0 < N) row_start[idx + 0] = excl;
  if (idx + 1 < N) row_start[idx + 1] = excl + a0;
  if (idx + 2 < N) row_start[idx + 2] = excl + a0 + a1;
  if (idx + 3 < N) row_start[idx + 3] = excl + a0 + a1 + a2;
  if (t == 255) bsums[blockIdx.x] = s[255];
}

// phase 2: serial exclusive scan of block sums (nb ~ 49); writes row_start[N] = total
__global__ void k_scan2(int* __restrict__ bsums, int* __restrict__ row_start, int nb, int N) {
  if (threadIdx.x == 0 && blockIdx.x == 0) {
    int run = 0;
    for (int i = 0; i < nb; ++i) {
      int v = bsums[i];
      bsums[i] = run;
      run += v;
    }
    row_start[N] = run;
  }
}

// phase 3: add block offsets; mirror into cursor
__global__ void k_scan3(int* __restrict__ row_start, int* __restrict__ cursor,
                        const int* __restrict__ bsums, int N) {
  int i = blockIdx.x * 256 + threadIdx.x;
  if (i < N) {
    int v = row_start[i] + bsums[i >> 10];
    row_start[i] = v;
    cursor[i] = v;
  }
}

__global__ void k_fill(const int* __restrict__ ei, int* cursor, int* __restrict__ csr_src,
                       int E, int N) {
  int i = blockIdx.x * 256 + threadIdx.x;
  if (i < E) {
    int s = ei[i], d = ei[E + i];
    int p = atomicAdd(&cursor[d], 1);
    csr_src[p] = s;
  } else if (i < E + N) {
    int n = i - E;
    int p = atomicAdd(&cursor[n], 1);
    csr_src[p] = n;
  }
}

// ---------------- fp32 -> fp16 convert ----------------
__global__ void k_tofp16(const float* __restrict__ src, fp16* __restrict__ dst, int n) {
  int i = blockIdx.x * 256 + threadIdx.x;
  if (i < n) dst[i] = (fp16)src[i];
}

// W [256k,256n] row-major -> Wt [n][k] fp16
__global__ void k_transpose_w(const float* __restrict__ W, fp16* __restrict__ Wt) {
  int k = blockIdx.x, n = threadIdx.x;
  Wt[n * 256 + k] = (fp16)W[k * 256 + n];
}

// concat head weights [Wmu|Wlv|Wa|pad] -> transposed fp16 [128][256] + bias_cat[128]
__global__ void k_build_head_w(const float* __restrict__ Wmu, const float* __restrict__ bmu,
                               const float* __restrict__ Wlv, const float* __restrict__ blv,
                               const float* __restrict__ Wa, const float* __restrict__ ba,
                               fp16* __restrict__ Wh, float* __restrict__ bias_cat) {
  int k = blockIdx.x, n = threadIdx.x;  // k 0..255, n 0..127
  float v = 0.f;
  if (n < 32) v = Wmu[k * 32 + n];
  else if (n < 64) v = Wlv[k * 32 + (n - 32)];
  else if (n < 94) v = Wa[k * 30 + (n - 64)];
  Wh[n * 256 + k] = (fp16)v;
  if (k == 0) {
    float b = 0.f;
    if (n < 32) b = bmu[n];
    else if (n < 64) b = blv[n - 32];
    else if (n < 94) b = ba[n - 64];
    bias_cat[n] = b;
  }
}

// ---------------- fp16 MFMA GEMM ----------------
// C[M,ldc] = A[M,256] @ Bt^T + bias. Output: fp32 Cf (with bias) OR fp16 C16 (no bias).
// When asrcp != null (layer GEMMs): fused per-node attention scores als/ald [N,4]
// (wave owns one head's 64 cols -> 16-lane shfl reduce, no atomics).
__global__ __launch_bounds__(256) void k_gemm(
    const fp16* __restrict__ A16, const fp16* __restrict__ B16,
    const float* __restrict__ bias, float* __restrict__ Cf, fp16* __restrict__ C16,
    const float* __restrict__ asrcp, const float* __restrict__ adstp,
    float* __restrict__ alsp, float* __restrict__ aldp,
    int M, int ldc) {
  __shared__ fp16 Ash[128 * 32];
  __shared__ fp16 Bsh[128 * 32];
  const int t = threadIdx.x;
  const int wave = t >> 6, lane = t & 63;
  const int m0 = blockIdx.x * 128, n0 = blockIdx.y * 128;
  const int lrow = lane & 15, lq = lane >> 4;
  const int wm = (wave >> 1) * 64, wn = (wave & 1) * 64;

  f32x4 acc[4][4] = {};

  const int j0 = wave * 64 + lane, j1 = j0 + 256;
  const int ar0 = j0 >> 2, ar1 = j1 >> 2;
  const int ak0 = ((j0 & 3) ^ ((ar0 >> 1) & 3)) * 8;
  const int ak1 = ((j1 & 3) ^ ((ar1 >> 1) & 3)) * 8;
  const int gm0 = min(m0 + ar0, M - 1), gm1 = min(m0 + ar1, M - 1);
  const size_t oa0 = (size_t)gm0 * 256 + ak0, oa1 = (size_t)gm1 * 256 + ak1;
  const size_t ob0 = (size_t)(n0 + ar0) * 256 + ak0, ob1 = (size_t)(n0 + ar1) * 256 + ak1;
  const int l0 = wave * 512, l1 = 2048 + wave * 512;

  for (int k0 = 0; k0 < 256; k0 += 32) {
    __syncthreads();
    gld_lds16(A16 + oa0 + k0, Ash + l0);
    gld_lds16(A16 + oa1 + k0, Ash + l1);
    gld_lds16(B16 + ob0 + k0, Bsh + l0);
    gld_lds16(B16 + ob1 + k0, Bsh + l1);
    __syncthreads();
    half8 af[4], bf[4];
#pragma unroll
    for (int mi = 0; mi < 4; mi++) {
      int row = wm + mi * 16 + lrow;
      int off = row * 32 + ((lq ^ ((row >> 1) & 3)) << 3);
      af[mi] = *(const half8*)(Ash + off);
    }
#pragma unroll
    for (int ni = 0; ni < 4; ni++) {
      int row = wn + ni * 16 + lrow;
      int off = row * 32 + ((lq ^ ((row >> 1) & 3)) << 3);
      bf[ni] = *(const half8*)(Bsh + off);
    }
#pragma unroll
    for (int mi = 0; mi < 4; mi++)
#pragma unroll
      for (int ni = 0; ni < 4; ni++)
        acc[mi][ni] = __builtin_amdgcn_mfma_f32_16x16x32_f16(af[mi], bf[ni], acc[mi][ni], 0, 0, 0);
  }

#pragma unroll
  for (int mi = 0; mi < 4; mi++) {
    const int mb = m0 + wm + mi * 16 + lq * 4;
#pragma unroll
    for (int ni = 0; ni < 4; ni++) {
      const int n = n0 + wn + ni * 16 + lrow;
#pragma unroll
      for (int r = 0; r < 4; r++) {
        int m = mb + r;
        if (m < M) {
          if (C16) C16[(size_t)m * ldc + n] = (fp16)acc[mi][ni][r];
          else     Cf[(size_t)m * ldc + n] = acc[mi][ni][r] + (bias ? bias[n] : 0.f);
        }
      }
    }
  }

  // ---- fused attention-score epilogue (layer GEMMs only) ----
  if (asrcp) {
    const int headg = (n0 + wn) >> 6;   // this wave's single head
    float as4[4], ad4[4];
#pragma unroll
    for (int ni = 0; ni < 4; ni++) {
      int cg = n0 + wn + ni * 16 + lrow;   // global col == flat [H*C] index
      as4[ni] = asrcp[cg];
      ad4[ni] = adstp[cg];
    }
#pragma unroll
    for (int mi = 0; mi < 4; mi++) {
      float ps[4] = {0.f, 0.f, 0.f, 0.f}, pd[4] = {0.f, 0.f, 0.f, 0.f};
#pragma unroll
      for (int ni = 0; ni < 4; ni++)
#pragma unroll
        for (int r = 0; r < 4; r++) {
          ps[r] += acc[mi][ni][r] * as4[ni];
          pd[r] += acc[mi][ni][r] * ad4[ni];
        }
      // reduce over the 16 lrow lanes (xor < 16 stays within the lq group)
#pragma unroll
      for (int o = 1; o < 16; o <<= 1)
#pragma unroll
        for (int r = 0; r < 4; r++) {
          ps[r] += __shfl_xor(ps[r], o, 64);
          pd[r] += __shfl_xor(pd[r], o, 64);
        }
      if (lrow == 0) {
#pragma unroll
        for (int r = 0; r < 4; r++) {
          int m = m0 + wm + mi * 16 + lq * 4 + r;
          if (m < M) {
            alsp[(size_t)m * 4 + headg] = ps[r];
            aldp[(size_t)m * 4 + headg] = pd[r];
          }
        }
      }
    }
  }
}

// -------- XCD-channel-split single-pass softmax-gather: 2 nodes/wave --------
// Blocks round-robin across 8 XCDs (xcd = blockIdx.x & 7). XCDs 0-3 process
// channel half 0 (bytes 0..255 of each 512B h-row = cache lines 0-1), XCDs 4-7
// half 1 (lines 2-3) -> each XCD's L2 random-access footprint is 12.8 MB, not
// 25.6 MB. R5's version failed because both halves co-ran on every XCD; this
// ties half to XCD in ONE dispatch. Node-group g covers [0,nb) per half via
// g = (b>>3)*4 + (b&3). No max-subtraction (e bounded, fp32-safe). Block 0
// zeroes BN stats (consumed by the later k_bn_stats/k_bn_apply).
__global__ __launch_bounds__(256) void k_gather(
    const fp16* __restrict__ h16, const float* __restrict__ als, const float* __restrict__ ald,
    const int* __restrict__ row_start, const int* __restrict__ csr_src,
    const float* __restrict__ bias, fp16* __restrict__ out, float* __restrict__ stats,
    int N, int nb) {
  if (blockIdx.x == 0) { stats[threadIdx.x] = 0.f; stats[256 + threadIdx.x] = 0.f; }
  const int b = blockIdx.x;
  const int xcd = b & 7;
  const int hc = xcd >> 2;                 // channel half for this XCD
  const int g = (b >> 3) * 4 + (xcd & 3);  // node-group index within the half
  if (g >= nb) return;
  const int wave = threadIdx.x >> 6, lane = threadIdx.x & 63;
  const int half = lane >> 5, l32 = lane & 31;
  const int n = g * 8 + wave * 2 + half;
  if (n >= N) return;
  const int c = hc * 128 + l32 * 4;        // global channel (4 per lane)
  const int head = c >> 6;
  const float adh = ald[(size_t)n * 4 + head];
  const int beg = row_start[n], end = row_start[n + 1];
  float s = 0.f;
  float a0 = 0.f, a1 = 0.f, a2 = 0.f, a3 = 0.f;
#pragma unroll 4
  for (int i = beg; i < end; ++i) {
    const int sidx = csr_src[i];
    float e = als[(size_t)sidx * 4 + head] + adh;
    e = e > 0.f ? e : NEG_SLOPE * e;
    const float w = __expf(e);
    s += w;
    const half4 hv = *(const half4*)(h16 + (size_t)sidx * 256 + c);
    a0 += w * (float)hv[0]; a1 += w * (float)hv[1];
    a2 += w * (float)hv[2]; a3 += w * (float)hv[3];
  }
  const float inv = 1.f / (s + 1e-16f);
  const float4 bb = *(const float4*)(bias + c);
  half4 o;
  o[0] = (fp16)(a0 * inv + bb.x); o[1] = (fp16)(a1 * inv + bb.y);
  o[2] = (fp16)(a2 * inv + bb.z); o[3] = (fp16)(a3 * inv + bb.w);
  *(half4*)(out + (size_t)n * 256 + c) = o;
}

// ---------------- batch norm (fp16 input) ----------------
__global__ __launch_bounds__(256) void k_bn_stats(const fp16* __restrict__ x,
                                                  float* __restrict__ stats, int N) {
  const int t = threadIdx.x;
  int r0 = blockIdx.x * 128;
  int rend = min(r0 + 128, N);
  float s = 0.f, sq = 0.f;
  for (int r = r0; r < rend; ++r) {
    float v = (float)x[(size_t)r * 256 + t];
    s += v; sq += v * v;
  }
  atomicAdd(&stats[t], s);
  atomicAdd(&stats[256 + t], sq);
}

// l<2: write fp16 act of relu(bn). l==2: encf += relu(bn) in-place AND write fp16
// act of the sum (feeds the head GEMM).
__global__ __launch_bounds__(256) void k_bn_apply(
    const fp16* __restrict__ x, const float* __restrict__ stats,
    const float* __restrict__ g, const float* __restrict__ be,
    fp16* __restrict__ act16, float* __restrict__ encf,
    float invN, int total) {
  int idx = blockIdx.x * 256 + threadIdx.x;
  if (idx >= total) return;
  int c = idx & 255;
  float mu = stats[c] * invN;
  float var = stats[256 + c] * invN - mu * mu;
  float v = ((float)x[idx] - mu) * rsqrtf(var + BN_EPS) * g[c] + be[c];
  v = fmaxf(v, 0.f);
  if (encf) { v += encf[idx]; encf[idx] = v; }
  act16[idx] = (fp16)v;
}

// ---------------- VAE finish: z, out = z@Wd, copy mu/lv/aux ----------------
__global__ __launch_bounds__(256) void k_finish(
    const float* __restrict__ HEAD, const float* __restrict__ eps,
    const float* __restrict__ Wd, const float* __restrict__ bd,
    float* __restrict__ o_out, float* __restrict__ o_mu, float* __restrict__ o_lv,
    float* __restrict__ o_aux, int N) {
  __shared__ float sWd[1024];
  __shared__ float sZ[8][33];
  const int t = threadIdx.x;
  for (int i = t; i < 1024; i += 256) sWd[i] = Wd[i];
  __syncthreads();
  const int r = t >> 5, j = t & 31;
  const int n = blockIdx.x * 8 + r;
  if (n < N) {
    const float* hp = HEAD + (size_t)n * 128;
    float mu = hp[j];
    float lv = hp[32 + j];
    float z = mu + eps[(size_t)n * 32 + j] * __expf(0.5f * lv);
    sZ[r][j] = z;
    o_mu[(size_t)n * 32 + j] = mu;
    o_lv[(size_t)n * 32 + j] = lv;
    if (j < 30) o_aux[(size_t)n * 30 + j] = hp[64 + j];
  }
  __syncthreads();
  if (n < N) {
    float o = bd[j];
#pragma unroll
    for (int k = 0; k < 32; ++k) o += sZ[r][k] * sWd[k * 32 + j];
    o_out[(size_t)n * 32 + j] = o;
  }
}

// ---------------- launcher ----------------
extern "C" void kernel_launch(void* const* d_in, const int* in_sizes, int n_in,
                              void* d_out, int out_size, void* d_ws, size_t ws_size,
                              hipStream_t stream) {
  const float* x   = (const float*)d_in[0];
  const int*   ei  = (const int*)d_in[1];
  const float* eps = (const float*)d_in[2];
  const float* Wg[3]   = {(const float*)d_in[3], (const float*)d_in[9],  (const float*)d_in[15]};
  const float* asrc[3] = {(const float*)d_in[4], (const float*)d_in[10], (const float*)d_in[16]};
  const float* adst[3] = {(const float*)d_in[5], (const float*)d_in[11], (const float*)d_in[17]};
  const float* bg[3]   = {(const float*)d_in[6], (const float*)d_in[12], (const float*)d_in[18]};
  const float* gam[3]  = {(const float*)d_in[7], (const float*)d_in[13], (const float*)d_in[19]};
  const float* bet[3]  = {(const float*)d_in[8], (const float*)d_in[14], (const float*)d_in[20]};
  const float* Wr  = (const float*)d_in[21];
  const float* br  = (const float*)d_in[22];
  const float* Wmu = (const float*)d_in[23];
  const float* bmu = (const float*)d_in[24];
  const float* Wlv = (const float*)d_in[25];
  const float* blv = (const float*)d_in[26];
  const float* Wd  = (const float*)d_in[27];
  const float* bd  = (const float*)d_in[28];
  const float* Wa  = (const float*)d_in[29];
  const float* ba  = (const float*)d_in[30];

  const int N = in_sizes[0] / 256;
  const int E = in_sizes[1] / 2;

  float* outp  = (float*)d_out;
  float* o_out = outp;
  float* o_mu  = outp + (size_t)N * 32;
  float* o_lv  = outp + (size_t)N * 64;
  float* o_aux = outp + (size_t)N * 96;
  float* o_enc = outp + (size_t)N * 96 + (size_t)N * 30;

  char* p = (char*)d_ws;
  auto carve = [&](size_t bytes) -> char* {
    char* r = p;
    p += (bytes + 255) & ~(size_t)255;
    return r;
  };
  int* counts    = (int*)carve((size_t)N * 4);
  int* row_start = (int*)carve(((size_t)N + 1) * 4);
  int* cursor    = (int*)carve((size_t)N * 4);
  int* csr_src   = (int*)carve((size_t)(E + N) * 4);
  int* bsums     = (int*)carve(((size_t)N / 1024 + 2) * 4);
  fp16* Wt16[4];
  for (int i = 0; i < 4; ++i) Wt16[i] = (fp16*)carve(256 * 256 * 2);
  fp16* Wh16 = (fp16*)carve(128 * 256 * 2);
  float* bias_cat = (float*)carve(128 * 4);
  fp16* A16 = (fp16*)carve((size_t)N * 256 * 2);    // activations fp16
  fp16* H16 = (fp16*)carve((size_t)N * 256 * 2);    // h in fp16 for gather
  float* FHEAD = (float*)carve((size_t)N * 128 * 4);  // head GEMM out
  fp16* AGG16 = (fp16*)carve((size_t)N * 256 * 2);  // GAT layer output (fp16)
  float* als = (float*)carve((size_t)N * 4 * 4);
  float* ald = (float*)carve((size_t)N * 4 * 4);
  float* stats = (float*)carve(512 * 4);

  dim3 b256(256);

  // CSR by dst (self-loops included as count init = 1)
  const int nb_scan = (N + 1023) / 1024;
  k_init_counts<<<(N + 255) / 256, b256, 0, stream>>>(counts, N);
  k_count<<<(E + 255) / 256, b256, 0, stream>>>(ei, counts, E);
  k_scan1<<<nb_scan, b256, 0, stream>>>(counts, row_start, bsums, N);
  k_scan2<<<1, 64, 0, stream>>>(bsums, row_start, nb_scan, N);
  k_scan3<<<(N + 255) / 256, b256, 0, stream>>>(row_start, cursor, bsums, N);
  k_fill<<<(E + N + 255) / 256, b256, 0, stream>>>(ei, cursor, csr_src, E, N);

  // conversions
  k_tofp16<<<((size_t)N * 256 + 255) / 256, b256, 0, stream>>>(x, A16, N * 256);
  k_transpose_w<<<256, b256, 0, stream>>>(Wr, Wt16[0]);
  for (int l = 0; l < 3; ++l)
    k_transpose_w<<<256, b256, 0, stream>>>(Wg[l], Wt16[l + 1]);
  k_build_head_w<<<256, dim3(128), 0, stream>>>(Wmu, bmu, Wlv, blv, Wa, ba, Wh16, bias_cat);

  dim3 ggrid((N + 127) / 128, 2);
  // residual = x @ Wr + br -> o_enc (bn3 adds relu(bn) in-place later)
  k_gemm<<<ggrid, b256, 0, stream>>>(A16, Wt16[0], br, o_enc, nullptr,
                                     nullptr, nullptr, nullptr, nullptr, N, 256);

  const float invN = 1.0f / (float)N;
  const int nb_gather = (N + 7) / 8;                       // node-groups (8 nodes each)
  const int grid_gather = 8 * ((nb_gather + 3) / 4);       // 8-block tiles: 4 per half
  for (int l = 0; l < 3; ++l) {
    // GEMM + fused als/ald epilogue
    k_gemm<<<ggrid, b256, 0, stream>>>(A16, Wt16[l + 1], nullptr, nullptr, H16,
                                       asrc[l], adst[l], als, ald, N, 256);
    k_gather<<<grid_gather, b256, 0, stream>>>(H16, als, ald, row_start, csr_src, bg[l],
                                               AGG16, stats, N, nb_gather);
    k_bn_stats<<<(N + 127) / 128, b256, 0, stream>>>(AGG16, stats, N);
    if (l < 2)
      k_bn_apply<<<((size_t)N * 256 + 255) / 256, b256, 0, stream>>>(
          AGG16, stats, gam[l], bet[l], A16, nullptr, invN, N * 256);
    else
      k_bn_apply<<<((size_t)N * 256 + 255) / 256, b256, 0, stream>>>(
          AGG16, stats, gam[l], bet[l], A16, o_enc, invN, N * 256);
  }

  // HEAD[N,128] = enc @ [Wmu|Wlv|Wa] + bias_cat (A16 = fp16(enc) from bn_apply l==2)
  dim3 hgrid((N + 127) / 128, 1);
  k_gemm<<<hgrid, b256, 0, stream>>>(A16, Wh16, bias_cat, FHEAD, nullptr,
                                     nullptr, nullptr, nullptr, nullptr, N, 128);
  k_finish<<<(N + 7) / 8, b256, 0, stream>>>(FHEAD, eps, Wd, bd, o_out, o_mu, o_lv, o_aux, N);
}

// Round 10
// 800.531 us; speedup vs baseline: 1.0207x; 1.0207x over previous
//
#include <hip/hip_runtime.h>
#include <cstdint>

typedef __bf16 bf16;
typedef float f32x4 __attribute__((ext_vector_type(4)));
typedef _Float16 fp16;
typedef _Float16 half8 __attribute__((ext_vector_type(8)));

#define NEG_SLOPE 0.2f
#define BN_EPS 1e-5f

// ---------------- async global->LDS (16B per lane, wave-uniform LDS base) ----------------
__device__ __forceinline__ void gld_lds16(const void* g, void* l) {
  auto gp = reinterpret_cast<const __attribute__((address_space(1))) unsigned int*>(
      reinterpret_cast<uintptr_t>(g));
  auto lp = reinterpret_cast<__attribute__((address_space(3))) unsigned int*>(
      reinterpret_cast<uintptr_t>(l));
  __builtin_amdgcn_global_load_lds(gp, lp, 16, 0, 0);
}

// ---------------- fused prep: W transposes + head W + x->fp16 + counts init ----------------
// blocks [0,1024): transpose 4 weight matrices (b>>8 selects, b&255 = k row)
// blocks [1024,1280): head-W concat+transpose (+bias_cat at k==0)
// blocks [1280,1280+xb): x -> fp16 (1024 elems/block)
// blocks [1280+xb, ...): counts = 1 (self-loop init)
__global__ __launch_bounds__(256) void k_prep(
    const float* __restrict__ Wr, const float* __restrict__ W1,
    const float* __restrict__ W2, const float* __restrict__ W3,
    fp16* __restrict__ Wt0, fp16* __restrict__ Wt1,
    fp16* __restrict__ Wt2, fp16* __restrict__ Wt3,
    const float* __restrict__ Wmu, const float* __restrict__ bmu,
    const float* __restrict__ Wlv, const float* __restrict__ blv,
    const float* __restrict__ Wa, const float* __restrict__ ba,
    fp16* __restrict__ Wh, float* __restrict__ bias_cat,
    const float* __restrict__ x, fp16* __restrict__ A16,
    int* __restrict__ counts, int N, int xb) {
  const int b = blockIdx.x, t = threadIdx.x;
  if (b < 1024) {
    const int m = b >> 8, k = b & 255;
    const float* W = (m == 0) ? Wr : (m == 1) ? W1 : (m == 2) ? W2 : W3;
    fp16* Wt = (m == 0) ? Wt0 : (m == 1) ? Wt1 : (m == 2) ? Wt2 : Wt3;
    Wt[t * 256 + k] = (fp16)W[k * 256 + t];
  } else if (b < 1280) {
    const int k = b - 1024;
    if (t < 128) {
      float v = 0.f;
      if (t < 32) v = Wmu[k * 32 + t];
      else if (t < 64) v = Wlv[k * 32 + (t - 32)];
      else if (t < 94) v = Wa[k * 30 + (t - 64)];
      Wh[t * 256 + k] = (fp16)v;
      if (k == 0) {
        float bb = 0.f;
        if (t < 32) bb = bmu[t];
        else if (t < 64) bb = blv[t - 32];
        else if (t < 94) bb = ba[t - 64];
        bias_cat[t] = bb;
      }
    }
  } else if (b < 1280 + xb) {
    const size_t base = (size_t)(b - 1280) * 1024 + t;
    const size_t total = (size_t)N * 256;
#pragma unroll
    for (int r = 0; r < 4; ++r) {
      size_t i = base + (size_t)r * 256;
      if (i < total) A16[i] = (fp16)x[i];
    }
  } else {
    const int i = (b - 1280 - xb) * 256 + t;
    if (i < N) counts[i] = 1;  // self-loop
  }
}

// ---------------- CSR build ----------------
__global__ void k_count(const int* __restrict__ ei, int* counts, int E) {
  int i = blockIdx.x * 256 + threadIdx.x;
  if (i < E) atomicAdd(&counts[ei[E + i]], 1);
}

// phase 1: each block scans 1024 counts; writes local exclusive prefix into row_start,
// block total into bsums[blockIdx]
__global__ __launch_bounds__(256) void k_scan1(const int* __restrict__ counts,
                                               int* __restrict__ row_start,
                                               int* __restrict__ bsums, int N) {
  __shared__ int s[256];
  const int t = threadIdx.x;
  const int idx = blockIdx.x * 1024 + t * 4;
  int a0 = (idx + 0 < N) ? counts[idx + 0] : 0;
  int a1 = (idx + 1 < N) ? counts[idx + 1] : 0;
  int a2 = (idx + 2 < N) ? counts[idx + 2] : 0;
  int a3 = (idx + 3 < N) ? counts[idx + 3] : 0;
  const int mysum = a0 + a1 + a2 + a3;
  s[t] = mysum;
  __syncthreads();
  for (int ofs = 1; ofs < 256; ofs <<= 1) {
    int v = (t >= ofs) ? s[t - ofs] : 0;
    __syncthreads();
    s[t] += v;
    __syncthreads();
  }
  int excl = s[t] - mysum;
  if (idx + 0 < N) row_start[idx + 0] = excl;
  if (idx + 1 < N) row_start[idx + 1] = excl + a0;
  if (idx + 2 < N) row_start[idx + 2] = excl + a0 + a1;
  if (idx + 3 < N) row_start[idx + 3] = excl + a0 + a1 + a2;
  if (t == 255) bsums[blockIdx.x] = s[255];
}

// phase 2: serial exclusive scan of block sums (nb ~ 49); writes row_start[N] = total
__global__ void k_scan2(int* __restrict__ bsums, int* __restrict__ row_start, int nb, int N) {
  if (threadIdx.x == 0 && blockIdx.x == 0) {
    int run = 0;
    for (int i = 0; i < nb; ++i) {
      int v = bsums[i];
      bsums[i] = run;
      run += v;
    }
    row_start[N] = run;
  }
}

// phase 3: add block offsets; mirror into cursor
__global__ void k_scan3(int* __restrict__ row_start, int* __restrict__ cursor,
                        const int* __restrict__ bsums, int N) {
  int i = blockIdx.x * 256 + threadIdx.x;
  if (i < N) {
    int v = row_start[i] + bsums[i >> 10];
    row_start[i] = v;
    cursor[i] = v;
  }
}

__global__ void k_fill(const int* __restrict__ ei, int* cursor, int* __restrict__ csr_src,
                       int E, int N) {
  int i = blockIdx.x * 256 + threadIdx.x;
  if (i < E) {
    int s = ei[i], d = ei[E + i];
    int p = atomicAdd(&cursor[d], 1);
    csr_src[p] = s;
  } else if (i < E + N) {
    int n = i - E;
    int p = atomicAdd(&cursor[n], 1);
    csr_src[p] = n;
  }
}

// ---------------- fp16 MFMA GEMM ----------------
// C[M,ldc] = A[M,256] @ Bt^T + bias. Output: fp32 Cf (with bias) OR fp16 C16 (no bias).
// When asrcp != null (layer GEMMs): fused per-node attention scores als/ald [N,4]
// (wave owns one head's 64 cols -> 16-lane shfl reduce, no atomics).
__global__ __launch_bounds__(256) void k_gemm(
    const fp16* __restrict__ A16, const fp16* __restrict__ B16,
    const float* __restrict__ bias, float* __restrict__ Cf, fp16* __restrict__ C16,
    const float* __restrict__ asrcp, const float* __restrict__ adstp,
    float* __restrict__ alsp, float* __restrict__ aldp,
    int M, int ldc) {
  __shared__ fp16 Ash[128 * 32];
  __shared__ fp16 Bsh[128 * 32];
  const int t = threadIdx.x;
  const int wave = t >> 6, lane = t & 63;
  const int m0 = blockIdx.x * 128, n0 = blockIdx.y * 128;
  const int lrow = lane & 15, lq = lane >> 4;
  const int wm = (wave >> 1) * 64, wn = (wave & 1) * 64;

  f32x4 acc[4][4] = {};

  const int j0 = wave * 64 + lane, j1 = j0 + 256;
  const int ar0 = j0 >> 2, ar1 = j1 >> 2;
  const int ak0 = ((j0 & 3) ^ ((ar0 >> 1) & 3)) * 8;
  const int ak1 = ((j1 & 3) ^ ((ar1 >> 1) & 3)) * 8;
  const int gm0 = min(m0 + ar0, M - 1), gm1 = min(m0 + ar1, M - 1);
  const size_t oa0 = (size_t)gm0 * 256 + ak0, oa1 = (size_t)gm1 * 256 + ak1;
  const size_t ob0 = (size_t)(n0 + ar0) * 256 + ak0, ob1 = (size_t)(n0 + ar1) * 256 + ak1;
  const int l0 = wave * 512, l1 = 2048 + wave * 512;

  for (int k0 = 0; k0 < 256; k0 += 32) {
    __syncthreads();
    gld_lds16(A16 + oa0 + k0, Ash + l0);
    gld_lds16(A16 + oa1 + k0, Ash + l1);
    gld_lds16(B16 + ob0 + k0, Bsh + l0);
    gld_lds16(B16 + ob1 + k0, Bsh + l1);
    __syncthreads();
    half8 af[4], bf[4];
#pragma unroll
    for (int mi = 0; mi < 4; mi++) {
      int row = wm + mi * 16 + lrow;
      int off = row * 32 + ((lq ^ ((row >> 1) & 3)) << 3);
      af[mi] = *(const half8*)(Ash + off);
    }
#pragma unroll
    for (int ni = 0; ni < 4; ni++) {
      int row = wn + ni * 16 + lrow;
      int off = row * 32 + ((lq ^ ((row >> 1) & 3)) << 3);
      bf[ni] = *(const half8*)(Bsh + off);
    }
#pragma unroll
    for (int mi = 0; mi < 4; mi++)
#pragma unroll
      for (int ni = 0; ni < 4; ni++)
        acc[mi][ni] = __builtin_amdgcn_mfma_f32_16x16x32_f16(af[mi], bf[ni], acc[mi][ni], 0, 0, 0);
  }

#pragma unroll
  for (int mi = 0; mi < 4; mi++) {
    const int mb = m0 + wm + mi * 16 + lq * 4;
#pragma unroll
    for (int ni = 0; ni < 4; ni++) {
      const int n = n0 + wn + ni * 16 + lrow;
#pragma unroll
      for (int r = 0; r < 4; r++) {
        int m = mb + r;
        if (m < M) {
          if (C16) C16[(size_t)m * ldc + n] = (fp16)acc[mi][ni][r];
          else     Cf[(size_t)m * ldc + n] = acc[mi][ni][r] + (bias ? bias[n] : 0.f);
        }
      }
    }
  }

  // ---- fused attention-score epilogue (layer GEMMs only) ----
  if (asrcp) {
    const int headg = (n0 + wn) >> 6;   // this wave's single head
    float as4[4], ad4[4];
#pragma unroll
    for (int ni = 0; ni < 4; ni++) {
      int cg = n0 + wn + ni * 16 + lrow;   // global col == flat [H*C] index
      as4[ni] = asrcp[cg];
      ad4[ni] = adstp[cg];
    }
#pragma unroll
    for (int mi = 0; mi < 4; mi++) {
      float ps[4] = {0.f, 0.f, 0.f, 0.f}, pd[4] = {0.f, 0.f, 0.f, 0.f};
#pragma unroll
      for (int ni = 0; ni < 4; ni++)
#pragma unroll
        for (int r = 0; r < 4; r++) {
          ps[r] += acc[mi][ni][r] * as4[ni];
          pd[r] += acc[mi][ni][r] * ad4[ni];
        }
      // reduce over the 16 lrow lanes (xor < 16 stays within the lq group)
#pragma unroll
      for (int o = 1; o < 16; o <<= 1)
#pragma unroll
        for (int r = 0; r < 4; r++) {
          ps[r] += __shfl_xor(ps[r], o, 64);
          pd[r] += __shfl_xor(pd[r], o, 64);
        }
      if (lrow == 0) {
#pragma unroll
        for (int r = 0; r < 4; r++) {
          int m = m0 + wm + mi * 16 + lq * 4 + r;
          if (m < M) {
            alsp[(size_t)m * 4 + headg] = ps[r];
            aldp[(size_t)m * 4 + headg] = pd[r];
          }
        }
      }
    }
  }
}

// -------- single-pass segment softmax + weighted gather: 2 nodes/wave --------
// (Round-5 verified structure: 65 us/dispatch — best of 3 measured variants.)
// No max-subtraction: e bounded, exp(e) fp32-safe, normalized softmax identical.
// Block 0 zeroes BN stats.
__global__ __launch_bounds__(256) void k_gather(
    const fp16* __restrict__ h16, const float* __restrict__ als, const float* __restrict__ ald,
    const int* __restrict__ row_start, const int* __restrict__ csr_src,
    const float* __restrict__ bias, fp16* __restrict__ out, float* __restrict__ stats, int N) {
  if (blockIdx.x == 0) { stats[threadIdx.x] = 0.f; stats[256 + threadIdx.x] = 0.f; }
  const int wave = threadIdx.x >> 6, lane = threadIdx.x & 63;
  const int half = lane >> 5, l32 = lane & 31;
  const int n = blockIdx.x * 8 + wave * 2 + half;
  if (n >= N) return;
  const int head = l32 >> 3;
  const int c0 = l32 * 8;
  const float adh = ald[(size_t)n * 4 + head];
  const int beg = row_start[n], end = row_start[n + 1];
  float s = 0.f;
  float acc[8] = {0.f, 0.f, 0.f, 0.f, 0.f, 0.f, 0.f, 0.f};
#pragma unroll 4
  for (int i = beg; i < end; ++i) {
    const int sidx = csr_src[i];
    float e = als[(size_t)sidx * 4 + head] + adh;
    e = e > 0.f ? e : NEG_SLOPE * e;
    const float w = __expf(e);
    s += w;
    const half8 hv = *(const half8*)(h16 + (size_t)sidx * 256 + c0);
#pragma unroll
    for (int k = 0; k < 8; ++k) acc[k] += w * (float)hv[k];
  }
  const float inv = 1.f / (s + 1e-16f);
  const float4 b1 = *(const float4*)(bias + c0);
  const float4 b2 = *(const float4*)(bias + c0 + 4);
  half8 o;
  o[0] = (fp16)(acc[0] * inv + b1.x); o[1] = (fp16)(acc[1] * inv + b1.y);
  o[2] = (fp16)(acc[2] * inv + b1.z); o[3] = (fp16)(acc[3] * inv + b1.w);
  o[4] = (fp16)(acc[4] * inv + b2.x); o[5] = (fp16)(acc[5] * inv + b2.y);
  o[6] = (fp16)(acc[6] * inv + b2.z); o[7] = (fp16)(acc[7] * inv + b2.w);
  *(half8*)(out + (size_t)n * 256 + c0) = o;
}

// ---------------- batch norm (fp16 input) ----------------
__global__ __launch_bounds__(256) void k_bn_stats(const fp16* __restrict__ x,
                                                  float* __restrict__ stats, int N) {
  const int t = threadIdx.x;
  int r0 = blockIdx.x * 128;
  int rend = min(r0 + 128, N);
  float s = 0.f, sq = 0.f;
  for (int r = r0; r < rend; ++r) {
    float v = (float)x[(size_t)r * 256 + t];
    s += v; sq += v * v;
  }
  atomicAdd(&stats[t], s);
  atomicAdd(&stats[256 + t], sq);
}

// l<2: write fp16 act of relu(bn). l==2: encf += relu(bn) in-place AND write fp16
// act of the sum (feeds the head GEMM).
__global__ __launch_bounds__(256) void k_bn_apply(
    const fp16* __restrict__ x, const float* __restrict__ stats,
    const float* __restrict__ g, const float* __restrict__ be,
    fp16* __restrict__ act16, float* __restrict__ encf,
    float invN, int total) {
  int idx = blockIdx.x * 256 + threadIdx.x;
  if (idx >= total) return;
  int c = idx & 255;
  float mu = stats[c] * invN;
  float var = stats[256 + c] * invN - mu * mu;
  float v = ((float)x[idx] - mu) * rsqrtf(var + BN_EPS) * g[c] + be[c];
  v = fmaxf(v, 0.f);
  if (encf) { v += encf[idx]; encf[idx] = v; }
  act16[idx] = (fp16)v;
}

// ---------------- VAE finish: z, out = z@Wd, copy mu/lv/aux ----------------
__global__ __launch_bounds__(256) void k_finish(
    const float* __restrict__ HEAD, const float* __restrict__ eps,
    const float* __restrict__ Wd, const float* __restrict__ bd,
    float* __restrict__ o_out, float* __restrict__ o_mu, float* __restrict__ o_lv,
    float* __restrict__ o_aux, int N) {
  __shared__ float sWd[1024];
  __shared__ float sZ[8][33];
  const int t = threadIdx.x;
  for (int i = t; i < 1024; i += 256) sWd[i] = Wd[i];
  __syncthreads();
  const int r = t >> 5, j = t & 31;
  const int n = blockIdx.x * 8 + r;
  if (n < N) {
    const float* hp = HEAD + (size_t)n * 128;
    float mu = hp[j];
    float lv = hp[32 + j];
    float z = mu + eps[(size_t)n * 32 + j] * __expf(0.5f * lv);
    sZ[r][j] = z;
    o_mu[(size_t)n * 32 + j] = mu;
    o_lv[(size_t)n * 32 + j] = lv;
    if (j < 30) o_aux[(size_t)n * 30 + j] = hp[64 + j];
  }
  __syncthreads();
  if (n < N) {
    float o = bd[j];
#pragma unroll
    for (int k = 0; k < 32; ++k) o += sZ[r][k] * sWd[k * 32 + j];
    o_out[(size_t)n * 32 + j] = o;
  }
}

// ---------------- launcher ----------------
extern "C" void kernel_launch(void* const* d_in, const int* in_sizes, int n_in,
                              void* d_out, int out_size, void* d_ws, size_t ws_size,
                              hipStream_t stream) {
  const float* x   = (const float*)d_in[0];
  const int*   ei  = (const int*)d_in[1];
  const float* eps = (const float*)d_in[2];
  const float* Wg[3]   = {(const float*)d_in[3], (const float*)d_in[9],  (const float*)d_in[15]};
  const float* asrc[3] = {(const float*)d_in[4], (const float*)d_in[10], (const float*)d_in[16]};
  const float* adst[3] = {(const float*)d_in[5], (const float*)d_in[11], (const float*)d_in[17]};
  const float* bg[3]   = {(const float*)d_in[6], (const float*)d_in[12], (const float*)d_in[18]};
  const float* gam[3]  = {(const float*)d_in[7], (const float*)d_in[13], (const float*)d_in[19]};
  const float* bet[3]  = {(const float*)d_in[8], (const float*)d_in[14], (const float*)d_in[20]};
  const float* Wr  = (const float*)d_in[21];
  const float* br  = (const float*)d_in[22];
  const float* Wmu = (const float*)d_in[23];
  const float* bmu = (const float*)d_in[24];
  const float* Wlv = (const float*)d_in[25];
  const float* blv = (const float*)d_in[26];
  const float* Wd  = (const float*)d_in[27];
  const float* bd  = (const float*)d_in[28];
  const float* Wa  = (const float*)d_in[29];
  const float* ba  = (const float*)d_in[30];

  const int N = in_sizes[0] / 256;
  const int E = in_sizes[1] / 2;

  float* outp  = (float*)d_out;
  float* o_out = outp;
  float* o_mu  = outp + (size_t)N * 32;
  float* o_lv  = outp + (size_t)N * 64;
  float* o_aux = outp + (size_t)N * 96;
  float* o_enc = outp + (size_t)N * 96 + (size_t)N * 30;

  char* p = (char*)d_ws;
  auto carve = [&](size_t bytes) -> char* {
    char* r = p;
    p += (bytes + 255) & ~(size_t)255;
    return r;
  };
  int* counts    = (int*)carve((size_t)N * 4);
  int* row_start = (int*)carve(((size_t)N + 1) * 4);
  int* cursor    = (int*)carve((size_t)N * 4);
  int* csr_src   = (int*)carve((size_t)(E + N) * 4);
  int* bsums     = (int*)carve(((size_t)N / 1024 + 2) * 4);
  fp16* Wt16[4];
  for (int i = 0; i < 4; ++i) Wt16[i] = (fp16*)carve(256 * 256 * 2);
  fp16* Wh16 = (fp16*)carve(128 * 256 * 2);
  float* bias_cat = (float*)carve(128 * 4);
  fp16* A16 = (fp16*)carve((size_t)N * 256 * 2);    // activations fp16
  fp16* H16 = (fp16*)carve((size_t)N * 256 * 2);    // h in fp16 for gather
  float* FHEAD = (float*)carve((size_t)N * 128 * 4);  // head GEMM out
  fp16* AGG16 = (fp16*)carve((size_t)N * 256 * 2);  // GAT layer output (fp16)
  float* als = (float*)carve((size_t)N * 4 * 4);
  float* ald = (float*)carve((size_t)N * 4 * 4);
  float* stats = (float*)carve(512 * 4);

  dim3 b256(256);

  // fused prep: 4 W transposes + head W + x->fp16 + counts init (was 7 dispatches)
  const int xb = ((int)((size_t)N * 256 + 1023)) / 1024;
  const int cb = (N + 255) / 256;
  k_prep<<<1280 + xb + cb, b256, 0, stream>>>(
      Wr, Wg[0], Wg[1], Wg[2], Wt16[0], Wt16[1], Wt16[2], Wt16[3],
      Wmu, bmu, Wlv, blv, Wa, ba, Wh16, bias_cat, x, A16, counts, N, xb);

  // CSR by dst (self-loops included via counts init = 1)
  const int nb_scan = (N + 1023) / 1024;
  k_count<<<(E + 255) / 256, b256, 0, stream>>>(ei, counts, E);
  k_scan1<<<nb_scan, b256, 0, stream>>>(counts, row_start, bsums, N);
  k_scan2<<<1, 64, 0, stream>>>(bsums, row_start, nb_scan, N);
  k_scan3<<<(N + 255) / 256, b256, 0, stream>>>(row_start, cursor, bsums, N);
  k_fill<<<(E + N + 255) / 256, b256, 0, stream>>>(ei, cursor, csr_src, E, N);

  dim3 ggrid((N + 127) / 128, 2);
  // residual = x @ Wr + br -> o_enc (bn3 adds relu(bn) in-place later)
  k_gemm<<<ggrid, b256, 0, stream>>>(A16, Wt16[0], br, o_enc, nullptr,
                                     nullptr, nullptr, nullptr, nullptr, N, 256);

  const float invN = 1.0f / (float)N;
  for (int l = 0; l < 3; ++l) {
    // GEMM + fused als/ald epilogue
    k_gemm<<<ggrid, b256, 0, stream>>>(A16, Wt16[l + 1], nullptr, nullptr, H16,
                                       asrc[l], adst[l], als, ald, N, 256);
    k_gather<<<(N + 7) / 8, b256, 0, stream>>>(H16, als, ald, row_start, csr_src, bg[l],
                                               AGG16, stats, N);
    k_bn_stats<<<(N + 127) / 128, b256, 0, stream>>>(AGG16, stats, N);
    if (l < 2)
      k_bn_apply<<<((size_t)N * 256 + 255) / 256, b256, 0, stream>>>(
          AGG16, stats, gam[l], bet[l], A16, nullptr, invN, N * 256);
    else
      k_bn_apply<<<((size_t)N * 256 + 255) / 256, b256, 0, stream>>>(
          AGG16, stats, gam[l], bet[l], A16, o_enc, invN, N * 256);
  }

  // HEAD[N,128] = enc @ [Wmu|Wlv|Wa] + bias_cat (A16 = fp16(enc) from bn_apply l==2)
  dim3 hgrid((N + 127) / 128, 1);
  k_gemm<<<hgrid, b256, 0, stream>>>(A16, Wh16, bias_cat, FHEAD, nullptr,
                                     nullptr, nullptr, nullptr, nullptr, N, 128);
  k_finish<<<(N + 7) / 8, b256, 0, stream>>>(FHEAD, eps, Wd, bd, o_out, o_mu, o_lv, o_aux, N);
}

// Round 11
// 787.506 us; speedup vs baseline: 1.0375x; 1.0165x over previous
//
#include <hip/hip_runtime.h>
#include <cstdint>

typedef __bf16 bf16;
typedef float f32x4 __attribute__((ext_vector_type(4)));
typedef _Float16 fp16;
typedef _Float16 half8 __attribute__((ext_vector_type(8)));

#define NEG_SLOPE 0.2f
#define BN_EPS 1e-5f

// ---------------- async global->LDS (16B per lane, wave-uniform LDS base) ----------------
__device__ __forceinline__ void gld_lds16(const void* g, void* l) {
  auto gp = reinterpret_cast<const __attribute__((address_space(1))) unsigned int*>(
      reinterpret_cast<uintptr_t>(g));
  auto lp = reinterpret_cast<__attribute__((address_space(3))) unsigned int*>(
      reinterpret_cast<uintptr_t>(l));
  __builtin_amdgcn_global_load_lds(gp, lp, 16, 0, 0);
}

// ---------------- fused prep: W transposes + head W + x->fp16 + counts init ----------------
__global__ __launch_bounds__(256) void k_prep(
    const float* __restrict__ Wr, const float* __restrict__ W1,
    const float* __restrict__ W2, const float* __restrict__ W3,
    fp16* __restrict__ Wt0, fp16* __restrict__ Wt1,
    fp16* __restrict__ Wt2, fp16* __restrict__ Wt3,
    const float* __restrict__ Wmu, const float* __restrict__ bmu,
    const float* __restrict__ Wlv, const float* __restrict__ blv,
    const float* __restrict__ Wa, const float* __restrict__ ba,
    fp16* __restrict__ Wh, float* __restrict__ bias_cat,
    const float* __restrict__ x, fp16* __restrict__ A16,
    int* __restrict__ counts, int N, int xb) {
  const int b = blockIdx.x, t = threadIdx.x;
  if (b < 1024) {
    const int m = b >> 8, k = b & 255;
    const float* W = (m == 0) ? Wr : (m == 1) ? W1 : (m == 2) ? W2 : W3;
    fp16* Wt = (m == 0) ? Wt0 : (m == 1) ? Wt1 : (m == 2) ? Wt2 : Wt3;
    Wt[t * 256 + k] = (fp16)W[k * 256 + t];
  } else if (b < 1280) {
    const int k = b - 1024;
    if (t < 128) {
      float v = 0.f;
      if (t < 32) v = Wmu[k * 32 + t];
      else if (t < 64) v = Wlv[k * 32 + (t - 32)];
      else if (t < 94) v = Wa[k * 30 + (t - 64)];
      Wh[t * 256 + k] = (fp16)v;
      if (k == 0) {
        float bb = 0.f;
        if (t < 32) bb = bmu[t];
        else if (t < 64) bb = blv[t - 32];
        else if (t < 94) bb = ba[t - 64];
        bias_cat[t] = bb;
      }
    }
  } else if (b < 1280 + xb) {
    const size_t base = (size_t)(b - 1280) * 1024 + t;
    const size_t total = (size_t)N * 256;
#pragma unroll
    for (int r = 0; r < 4; ++r) {
      size_t i = base + (size_t)r * 256;
      if (i < total) A16[i] = (fp16)x[i];
    }
  } else {
    const int i = (b - 1280 - xb) * 256 + t;
    if (i < N) counts[i] = 1;  // self-loop
  }
}

// ---------------- CSR build ----------------
__global__ void k_count(const int* __restrict__ ei, int* counts, int E) {
  int i = blockIdx.x * 256 + threadIdx.x;
  if (i < E) atomicAdd(&counts[ei[E + i]], 1);
}

__global__ __launch_bounds__(256) void k_scan1(const int* __restrict__ counts,
                                               int* __restrict__ row_start,
                                               int* __restrict__ bsums, int N) {
  __shared__ int s[256];
  const int t = threadIdx.x;
  const int idx = blockIdx.x * 1024 + t * 4;
  int a0 = (idx + 0 < N) ? counts[idx + 0] : 0;
  int a1 = (idx + 1 < N) ? counts[idx + 1] : 0;
  int a2 = (idx + 2 < N) ? counts[idx + 2] : 0;
  int a3 = (idx + 3 < N) ? counts[idx + 3] : 0;
  const int mysum = a0 + a1 + a2 + a3;
  s[t] = mysum;
  __syncthreads();
  for (int ofs = 1; ofs < 256; ofs <<= 1) {
    int v = (t >= ofs) ? s[t - ofs] : 0;
    __syncthreads();
    s[t] += v;
    __syncthreads();
  }
  int excl = s[t] - mysum;
  if (idx + 0 < N) row_start[idx + 0] = excl;
  if (idx + 1 < N) row_start[idx + 1] = excl + a0;
  if (idx + 2 < N) row_start[idx + 2] = excl + a0 + a1;
  if (idx + 3 < N) row_start[idx + 3] = excl + a0 + a1 + a2;
  if (t == 255) bsums[blockIdx.x] = s[255];
}

__global__ void k_scan2(int* __restrict__ bsums, int* __restrict__ row_start, int nb, int N) {
  if (threadIdx.x == 0 && blockIdx.x == 0) {
    int run = 0;
    for (int i = 0; i < nb; ++i) {
      int v = bsums[i];
      bsums[i] = run;
      run += v;
    }
    row_start[N] = run;
  }
}

__global__ void k_scan3(int* __restrict__ row_start, int* __restrict__ cursor,
                        const int* __restrict__ bsums, int N) {
  int i = blockIdx.x * 256 + threadIdx.x;
  if (i < N) {
    int v = row_start[i] + bsums[i >> 10];
    row_start[i] = v;
    cursor[i] = v;
  }
}

__global__ void k_fill(const int* __restrict__ ei, int* cursor, int* __restrict__ csr_src,
                       int E, int N) {
  int i = blockIdx.x * 256 + threadIdx.x;
  if (i < E) {
    int s = ei[i], d = ei[E + i];
    int p = atomicAdd(&cursor[d], 1);
    csr_src[p] = s;
  } else if (i < E + N) {
    int n = i - E;
    int p = atomicAdd(&cursor[n], 1);
    csr_src[p] = n;
  }
}

// ---------------- fp16 MFMA GEMM (256-wide outputs, pair-swizzled grid) ----------------
// 1D grid; pair (m-panel) members j=0/1 get ids == same (mod 8), 8 apart -> same XCD
// back-to-back under round-robin -> second read of the A panel hits that XCD's L2.
// When asrcp != null: fused per-node attention scores als/ald [N,4].
__global__ __launch_bounds__(256) void k_gemm(
    const fp16* __restrict__ A16, const fp16* __restrict__ B16,
    const float* __restrict__ bias, float* __restrict__ Cf, fp16* __restrict__ C16,
    const float* __restrict__ asrcp, const float* __restrict__ adstp,
    float* __restrict__ alsp, float* __restrict__ aldp,
    int M, int ldc) {
  __shared__ fp16 Ash[128 * 32];
  __shared__ fp16 Bsh[128 * 32];
  const int nmb = (M + 127) >> 7;
  const int b = blockIdx.x;
  const int xcd = b & 7, q = b >> 3;
  const int jn = q & 1, pmb = (q >> 1) * 8 + xcd;
  if (pmb >= nmb) return;
  const int t = threadIdx.x;
  const int wave = t >> 6, lane = t & 63;
  const int m0 = pmb * 128, n0 = jn * 128;
  const int lrow = lane & 15, lq = lane >> 4;
  const int wm = (wave >> 1) * 64, wn = (wave & 1) * 64;

  f32x4 acc[4][4] = {};

  const int j0 = wave * 64 + lane, j1 = j0 + 256;
  const int ar0 = j0 >> 2, ar1 = j1 >> 2;
  const int ak0 = ((j0 & 3) ^ ((ar0 >> 1) & 3)) * 8;
  const int ak1 = ((j1 & 3) ^ ((ar1 >> 1) & 3)) * 8;
  const int gm0 = min(m0 + ar0, M - 1), gm1 = min(m0 + ar1, M - 1);
  const size_t oa0 = (size_t)gm0 * 256 + ak0, oa1 = (size_t)gm1 * 256 + ak1;
  const size_t ob0 = (size_t)(n0 + ar0) * 256 + ak0, ob1 = (size_t)(n0 + ar1) * 256 + ak1;
  const int l0 = wave * 512, l1 = 2048 + wave * 512;

  for (int k0 = 0; k0 < 256; k0 += 32) {
    __syncthreads();
    gld_lds16(A16 + oa0 + k0, Ash + l0);
    gld_lds16(A16 + oa1 + k0, Ash + l1);
    gld_lds16(B16 + ob0 + k0, Bsh + l0);
    gld_lds16(B16 + ob1 + k0, Bsh + l1);
    __syncthreads();
    half8 af[4], bf[4];
#pragma unroll
    for (int mi = 0; mi < 4; mi++) {
      int row = wm + mi * 16 + lrow;
      int off = row * 32 + ((lq ^ ((row >> 1) & 3)) << 3);
      af[mi] = *(const half8*)(Ash + off);
    }
#pragma unroll
    for (int ni = 0; ni < 4; ni++) {
      int row = wn + ni * 16 + lrow;
      int off = row * 32 + ((lq ^ ((row >> 1) & 3)) << 3);
      bf[ni] = *(const half8*)(Bsh + off);
    }
#pragma unroll
    for (int mi = 0; mi < 4; mi++)
#pragma unroll
      for (int ni = 0; ni < 4; ni++)
        acc[mi][ni] = __builtin_amdgcn_mfma_f32_16x16x32_f16(af[mi], bf[ni], acc[mi][ni], 0, 0, 0);
  }

#pragma unroll
  for (int mi = 0; mi < 4; mi++) {
    const int mb = m0 + wm + mi * 16 + lq * 4;
#pragma unroll
    for (int ni = 0; ni < 4; ni++) {
      const int n = n0 + wn + ni * 16 + lrow;
#pragma unroll
      for (int r = 0; r < 4; r++) {
        int m = mb + r;
        if (m < M) {
          if (C16) C16[(size_t)m * ldc + n] = (fp16)acc[mi][ni][r];
          else     Cf[(size_t)m * ldc + n] = acc[mi][ni][r] + (bias ? bias[n] : 0.f);
        }
      }
    }
  }

  // ---- fused attention-score epilogue (layer GEMMs only) ----
  if (asrcp) {
    const int headg = (n0 + wn) >> 6;
    float as4[4], ad4[4];
#pragma unroll
    for (int ni = 0; ni < 4; ni++) {
      int cg = n0 + wn + ni * 16 + lrow;
      as4[ni] = asrcp[cg];
      ad4[ni] = adstp[cg];
    }
#pragma unroll
    for (int mi = 0; mi < 4; mi++) {
      float ps[4] = {0.f, 0.f, 0.f, 0.f}, pd[4] = {0.f, 0.f, 0.f, 0.f};
#pragma unroll
      for (int ni = 0; ni < 4; ni++)
#pragma unroll
        for (int r = 0; r < 4; r++) {
          ps[r] += acc[mi][ni][r] * as4[ni];
          pd[r] += acc[mi][ni][r] * ad4[ni];
        }
#pragma unroll
      for (int o = 1; o < 16; o <<= 1)
#pragma unroll
        for (int r = 0; r < 4; r++) {
          ps[r] += __shfl_xor(ps[r], o, 64);
          pd[r] += __shfl_xor(pd[r], o, 64);
        }
      if (lrow == 0) {
#pragma unroll
        for (int r = 0; r < 4; r++) {
          int m = m0 + wm + mi * 16 + lq * 4 + r;
          if (m < M) {
            alsp[(size_t)m * 4 + headg] = ps[r];
            aldp[(size_t)m * 4 + headg] = pd[r];
          }
        }
      }
    }
  }
}

// ---------------- head GEMM with fused VAE finish ----------------
// [N,128] = A16 @ Wh^T + bias_cat; cols 0-31 mu, 32-63 lv, 64-93 aux.
// wn==0 waves hold mu AND lv for the same row/col in the same thread ->
// z computed in-register, staged to LDS; out = z@Wd + bd done in-block.
// Eliminates FHEAD buffer (51 MB r/w) and the k_finish dispatch.
__global__ __launch_bounds__(256) void k_gemm_head(
    const fp16* __restrict__ A16, const fp16* __restrict__ B16,
    const float* __restrict__ bias_cat, const float* __restrict__ eps,
    const float* __restrict__ Wd, const float* __restrict__ bd,
    float* __restrict__ o_out, float* __restrict__ o_mu, float* __restrict__ o_lv,
    float* __restrict__ o_aux, int M) {
  __shared__ fp16 Ash[128 * 32];
  __shared__ fp16 Bsh[128 * 32];
  __shared__ float sZ[128][33];
  __shared__ float sWd[1024];
  const int t = threadIdx.x;
  const int wave = t >> 6, lane = t & 63;
  const int m0 = blockIdx.x * 128;
  const int lrow = lane & 15, lq = lane >> 4;
  const int wm = (wave >> 1) * 64, wn = (wave & 1) * 64;

  f32x4 acc[4][4] = {};

  const int j0 = wave * 64 + lane, j1 = j0 + 256;
  const int ar0 = j0 >> 2, ar1 = j1 >> 2;
  const int ak0 = ((j0 & 3) ^ ((ar0 >> 1) & 3)) * 8;
  const int ak1 = ((j1 & 3) ^ ((ar1 >> 1) & 3)) * 8;
  const int gm0 = min(m0 + ar0, M - 1), gm1 = min(m0 + ar1, M - 1);
  const size_t oa0 = (size_t)gm0 * 256 + ak0, oa1 = (size_t)gm1 * 256 + ak1;
  const size_t ob0 = (size_t)ar0 * 256 + ak0, ob1 = (size_t)ar1 * 256 + ak1;
  const int l0 = wave * 512, l1 = 2048 + wave * 512;

  for (int k0 = 0; k0 < 256; k0 += 32) {
    __syncthreads();
    gld_lds16(A16 + oa0 + k0, Ash + l0);
    gld_lds16(A16 + oa1 + k0, Ash + l1);
    gld_lds16(B16 + ob0 + k0, Bsh + l0);
    gld_lds16(B16 + ob1 + k0, Bsh + l1);
    __syncthreads();
    half8 af[4], bf[4];
#pragma unroll
    for (int mi = 0; mi < 4; mi++) {
      int row = wm + mi * 16 + lrow;
      int off = row * 32 + ((lq ^ ((row >> 1) & 3)) << 3);
      af[mi] = *(const half8*)(Ash + off);
    }
#pragma unroll
    for (int ni = 0; ni < 4; ni++) {
      int row = wn + ni * 16 + lrow;
      int off = row * 32 + ((lq ^ ((row >> 1) & 3)) << 3);
      bf[ni] = *(const half8*)(Bsh + off);
    }
#pragma unroll
    for (int mi = 0; mi < 4; mi++)
#pragma unroll
      for (int ni = 0; ni < 4; ni++)
        acc[mi][ni] = __builtin_amdgcn_mfma_f32_16x16x32_f16(af[mi], bf[ni], acc[mi][ni], 0, 0, 0);
  }

  // cooperative Wd load (32x32, row-major)
  for (int i = t; i < 1024; i += 256) sWd[i] = Wd[i];

  if ((wave & 1) == 0) {
    // wn == 0: cols 0..63. ni=0,1 -> mu col j; ni+2 -> lv col j (same j!).
#pragma unroll
    for (int mi = 0; mi < 4; mi++) {
      const int lrb = wm + mi * 16 + lq * 4;   // local row base
      const int mb = m0 + lrb;
#pragma unroll
      for (int ni = 0; ni < 2; ni++) {
        const int jj = ni * 16 + lrow;          // 0..31
#pragma unroll
        for (int r = 0; r < 4; r++) {
          const int m = mb + r;
          if (m < M) {
            float mu = acc[mi][ni][r] + bias_cat[jj];
            float lv = acc[mi][ni + 2][r] + bias_cat[32 + jj];
            float z = mu + eps[(size_t)m * 32 + jj] * __expf(0.5f * lv);
            o_mu[(size_t)m * 32 + jj] = mu;
            o_lv[(size_t)m * 32 + jj] = lv;
            sZ[lrb + r][jj] = z;
          }
        }
      }
    }
  } else {
    // wn == 1: cols 64..127 -> aux (64..93)
#pragma unroll
    for (int mi = 0; mi < 4; mi++) {
      const int mb = m0 + wm + mi * 16 + lq * 4;
#pragma unroll
      for (int ni = 0; ni < 4; ni++) {
        const int n = 64 + ni * 16 + lrow;
        if (n < 94) {
#pragma unroll
          for (int r = 0; r < 4; r++) {
            const int m = mb + r;
            if (m < M) o_aux[(size_t)m * 30 + (n - 64)] = acc[mi][ni][r] + bias_cat[n];
          }
        }
      }
    }
  }
  __syncthreads();
  // out = z @ Wd + bd : 8 rows x 32 cols per iteration, 16 iterations
  const int jc = t & 31, rr = t >> 5;
#pragma unroll
  for (int it = 0; it < 16; ++it) {
    const int lr = it * 8 + rr;
    const int m = m0 + lr;
    if (m < M) {
      float o = bd[jc];
#pragma unroll
      for (int k = 0; k < 32; ++k) o += sZ[lr][k] * sWd[k * 32 + jc];
      o_out[(size_t)m * 32 + jc] = o;
    }
  }
}

// -------- single-pass segment softmax + weighted gather: 2 nodes/wave --------
// (Round-5 verified structure: 65 us/dispatch — best of 3 measured variants.)
__global__ __launch_bounds__(256) void k_gather(
    const fp16* __restrict__ h16, const float* __restrict__ als, const float* __restrict__ ald,
    const int* __restrict__ row_start, const int* __restrict__ csr_src,
    const float* __restrict__ bias, fp16* __restrict__ out, float* __restrict__ stats, int N) {
  if (blockIdx.x == 0) { stats[threadIdx.x] = 0.f; stats[256 + threadIdx.x] = 0.f; }
  const int wave = threadIdx.x >> 6, lane = threadIdx.x & 63;
  const int half = lane >> 5, l32 = lane & 31;
  const int n = blockIdx.x * 8 + wave * 2 + half;
  if (n >= N) return;
  const int head = l32 >> 3;
  const int c0 = l32 * 8;
  const float adh = ald[(size_t)n * 4 + head];
  const int beg = row_start[n], end = row_start[n + 1];
  float s = 0.f;
  float acc[8] = {0.f, 0.f, 0.f, 0.f, 0.f, 0.f, 0.f, 0.f};
#pragma unroll 4
  for (int i = beg; i < end; ++i) {
    const int sidx = csr_src[i];
    float e = als[(size_t)sidx * 4 + head] + adh;
    e = e > 0.f ? e : NEG_SLOPE * e;
    const float w = __expf(e);
    s += w;
    const half8 hv = *(const half8*)(h16 + (size_t)sidx * 256 + c0);
#pragma unroll
    for (int k = 0; k < 8; ++k) acc[k] += w * (float)hv[k];
  }
  const float inv = 1.f / (s + 1e-16f);
  const float4 b1 = *(const float4*)(bias + c0);
  const float4 b2 = *(const float4*)(bias + c0 + 4);
  half8 o;
  o[0] = (fp16)(acc[0] * inv + b1.x); o[1] = (fp16)(acc[1] * inv + b1.y);
  o[2] = (fp16)(acc[2] * inv + b1.z); o[3] = (fp16)(acc[3] * inv + b1.w);
  o[4] = (fp16)(acc[4] * inv + b2.x); o[5] = (fp16)(acc[5] * inv + b2.y);
  o[6] = (fp16)(acc[6] * inv + b2.z); o[7] = (fp16)(acc[7] * inv + b2.w);
  *(half8*)(out + (size_t)n * 256 + c0) = o;
}

// ---------------- batch norm (fp16 input) ----------------
__global__ __launch_bounds__(256) void k_bn_stats(const fp16* __restrict__ x,
                                                  float* __restrict__ stats, int N) {
  const int t = threadIdx.x;
  int r0 = blockIdx.x * 128;
  int rend = min(r0 + 128, N);
  float s = 0.f, sq = 0.f;
  for (int r = r0; r < rend; ++r) {
    float v = (float)x[(size_t)r * 256 + t];
    s += v; sq += v * v;
  }
  atomicAdd(&stats[t], s);
  atomicAdd(&stats[256 + t], sq);
}

__global__ __launch_bounds__(256) void k_bn_apply(
    const fp16* __restrict__ x, const float* __restrict__ stats,
    const float* __restrict__ g, const float* __restrict__ be,
    fp16* __restrict__ act16, float* __restrict__ encf,
    float invN, int total) {
  int idx = blockIdx.x * 256 + threadIdx.x;
  if (idx >= total) return;
  int c = idx & 255;
  float mu = stats[c] * invN;
  float var = stats[256 + c] * invN - mu * mu;
  float v = ((float)x[idx] - mu) * rsqrtf(var + BN_EPS) * g[c] + be[c];
  v = fmaxf(v, 0.f);
  if (encf) { v += encf[idx]; encf[idx] = v; }
  act16[idx] = (fp16)v;
}

// ---------------- launcher ----------------
extern "C" void kernel_launch(void* const* d_in, const int* in_sizes, int n_in,
                              void* d_out, int out_size, void* d_ws, size_t ws_size,
                              hipStream_t stream) {
  const float* x   = (const float*)d_in[0];
  const int*   ei  = (const int*)d_in[1];
  const float* eps = (const float*)d_in[2];
  const float* Wg[3]   = {(const float*)d_in[3], (const float*)d_in[9],  (const float*)d_in[15]};
  const float* asrc[3] = {(const float*)d_in[4], (const float*)d_in[10], (const float*)d_in[16]};
  const float* adst[3] = {(const float*)d_in[5], (const float*)d_in[11], (const float*)d_in[17]};
  const float* bg[3]   = {(const float*)d_in[6], (const float*)d_in[12], (const float*)d_in[18]};
  const float* gam[3]  = {(const float*)d_in[7], (const float*)d_in[13], (const float*)d_in[19]};
  const float* bet[3]  = {(const float*)d_in[8], (const float*)d_in[14], (const float*)d_in[20]};
  const float* Wr  = (const float*)d_in[21];
  const float* br  = (const float*)d_in[22];
  const float* Wmu = (const float*)d_in[23];
  const float* bmu = (const float*)d_in[24];
  const float* Wlv = (const float*)d_in[25];
  const float* blv = (const float*)d_in[26];
  const float* Wd  = (const float*)d_in[27];
  const float* bd  = (const float*)d_in[28];
  const float* Wa  = (const float*)d_in[29];
  const float* ba  = (const float*)d_in[30];

  const int N = in_sizes[0] / 256;
  const int E = in_sizes[1] / 2;

  float* outp  = (float*)d_out;
  float* o_out = outp;
  float* o_mu  = outp + (size_t)N * 32;
  float* o_lv  = outp + (size_t)N * 64;
  float* o_aux = outp + (size_t)N * 96;
  float* o_enc = outp + (size_t)N * 96 + (size_t)N * 30;

  char* p = (char*)d_ws;
  auto carve = [&](size_t bytes) -> char* {
    char* r = p;
    p += (bytes + 255) & ~(size_t)255;
    return r;
  };
  int* counts    = (int*)carve((size_t)N * 4);
  int* row_start = (int*)carve(((size_t)N + 1) * 4);
  int* cursor    = (int*)carve((size_t)N * 4);
  int* csr_src   = (int*)carve((size_t)(E + N) * 4);
  int* bsums     = (int*)carve(((size_t)N / 1024 + 2) * 4);
  fp16* Wt16[4];
  for (int i = 0; i < 4; ++i) Wt16[i] = (fp16*)carve(256 * 256 * 2);
  fp16* Wh16 = (fp16*)carve(128 * 256 * 2);
  float* bias_cat = (float*)carve(128 * 4);
  fp16* A16 = (fp16*)carve((size_t)N * 256 * 2);    // activations fp16
  fp16* H16 = (fp16*)carve((size_t)N * 256 * 2);    // h in fp16 for gather
  fp16* AGG16 = (fp16*)carve((size_t)N * 256 * 2);  // GAT layer output (fp16)
  float* als = (float*)carve((size_t)N * 4 * 4);
  float* ald = (float*)carve((size_t)N * 4 * 4);
  float* stats = (float*)carve(512 * 4);

  dim3 b256(256);

  // fused prep: 4 W transposes + head W + x->fp16 + counts init
  const int xb = ((int)((size_t)N * 256 + 1023)) / 1024;
  const int cb = (N + 255) / 256;
  k_prep<<<1280 + xb + cb, b256, 0, stream>>>(
      Wr, Wg[0], Wg[1], Wg[2], Wt16[0], Wt16[1], Wt16[2], Wt16[3],
      Wmu, bmu, Wlv, blv, Wa, ba, Wh16, bias_cat, x, A16, counts, N, xb);

  // CSR by dst (self-loops included via counts init = 1)
  const int nb_scan = (N + 1023) / 1024;
  k_count<<<(E + 255) / 256, b256, 0, stream>>>(ei, counts, E);
  k_scan1<<<nb_scan, b256, 0, stream>>>(counts, row_start, bsums, N);
  k_scan2<<<1, 64, 0, stream>>>(bsums, row_start, nb_scan, N);
  k_scan3<<<(N + 255) / 256, b256, 0, stream>>>(row_start, cursor, bsums, N);
  k_fill<<<(E + N + 255) / 256, b256, 0, stream>>>(ei, cursor, csr_src, E, N);

  // pair-swizzled 1D grid for 256-wide GEMMs
  const int nmb = (N + 127) / 128;
  const int g1d = 8 * ((nmb + 7) / 8) * 2;
  // residual = x @ Wr + br -> o_enc (bn3 adds relu(bn) in-place later)
  k_gemm<<<g1d, b256, 0, stream>>>(A16, Wt16[0], br, o_enc, nullptr,
                                   nullptr, nullptr, nullptr, nullptr, N, 256);

  const float invN = 1.0f / (float)N;
  for (int l = 0; l < 3; ++l) {
    // GEMM + fused als/ald epilogue
    k_gemm<<<g1d, b256, 0, stream>>>(A16, Wt16[l + 1], nullptr, nullptr, H16,
                                     asrc[l], adst[l], als, ald, N, 256);
    k_gather<<<(N + 7) / 8, b256, 0, stream>>>(H16, als, ald, row_start, csr_src, bg[l],
                                               AGG16, stats, N);
    k_bn_stats<<<(N + 127) / 128, b256, 0, stream>>>(AGG16, stats, N);
    if (l < 2)
      k_bn_apply<<<((size_t)N * 256 + 255) / 256, b256, 0, stream>>>(
          AGG16, stats, gam[l], bet[l], A16, nullptr, invN, N * 256);
    else
      k_bn_apply<<<((size_t)N * 256 + 255) / 256, b256, 0, stream>>>(
          AGG16, stats, gam[l], bet[l], A16, o_enc, invN, N * 256);
  }

  // head GEMM with fused VAE finish (no FHEAD, no k_finish)
  k_gemm_head<<<nmb, b256, 0, stream>>>(A16, Wh16, bias_cat, eps, Wd, bd,
                                        o_out, o_mu, o_lv, o_aux, N);
}

// Round 12
// 743.445 us; speedup vs baseline: 1.0990x; 1.0593x over previous
//
#include <hip/hip_runtime.h>
#include <cstdint>

typedef __bf16 bf16;
typedef float f32x4 __attribute__((ext_vector_type(4)));
typedef _Float16 fp16;
typedef _Float16 half8 __attribute__((ext_vector_type(8)));
typedef _Float16 half4 __attribute__((ext_vector_type(4)));

#define NEG_SLOPE 0.2f
#define BN_EPS 1e-5f

// ---------------- async global->LDS (16B per lane, wave-uniform LDS base) ----------------
__device__ __forceinline__ void gld_lds16(const void* g, void* l) {
  auto gp = reinterpret_cast<const __attribute__((address_space(1))) unsigned int*>(
      reinterpret_cast<uintptr_t>(g));
  auto lp = reinterpret_cast<__attribute__((address_space(3))) unsigned int*>(
      reinterpret_cast<uintptr_t>(l));
  __builtin_amdgcn_global_load_lds(gp, lp, 16, 0, 0);
}

// ---------------- fused prep: W transposes + head W + x->fp16 + counts init ----------------
__global__ __launch_bounds__(256) void k_prep(
    const float* __restrict__ Wr, const float* __restrict__ W1,
    const float* __restrict__ W2, const float* __restrict__ W3,
    fp16* __restrict__ Wt0, fp16* __restrict__ Wt1,
    fp16* __restrict__ Wt2, fp16* __restrict__ Wt3,
    const float* __restrict__ Wmu, const float* __restrict__ bmu,
    const float* __restrict__ Wlv, const float* __restrict__ blv,
    const float* __restrict__ Wa, const float* __restrict__ ba,
    fp16* __restrict__ Wh, float* __restrict__ bias_cat,
    const float* __restrict__ x, fp16* __restrict__ A16,
    int* __restrict__ counts, int N, int xb) {
  const int b = blockIdx.x, t = threadIdx.x;
  if (b < 1024) {
    const int m = b >> 8, k = b & 255;
    const float* W = (m == 0) ? Wr : (m == 1) ? W1 : (m == 2) ? W2 : W3;
    fp16* Wt = (m == 0) ? Wt0 : (m == 1) ? Wt1 : (m == 2) ? Wt2 : Wt3;
    Wt[t * 256 + k] = (fp16)W[k * 256 + t];
  } else if (b < 1280) {
    const int k = b - 1024;
    if (t < 128) {
      float v = 0.f;
      if (t < 32) v = Wmu[k * 32 + t];
      else if (t < 64) v = Wlv[k * 32 + (t - 32)];
      else if (t < 94) v = Wa[k * 30 + (t - 64)];
      Wh[t * 256 + k] = (fp16)v;
      if (k == 0) {
        float bb = 0.f;
        if (t < 32) bb = bmu[t];
        else if (t < 64) bb = blv[t - 32];
        else if (t < 94) bb = ba[t - 64];
        bias_cat[t] = bb;
      }
    }
  } else if (b < 1280 + xb) {
    // vectorized x -> fp16: float4 load, half4 store (1024 elems/block)
    const size_t i0 = (size_t)(b - 1280) * 1024 + (size_t)t * 4;
    const size_t total = (size_t)N * 256;
    if (i0 + 3 < total) {
      const float4 v = *(const float4*)(x + i0);
      half4 h;
      h[0] = (fp16)v.x; h[1] = (fp16)v.y; h[2] = (fp16)v.z; h[3] = (fp16)v.w;
      *(half4*)(A16 + i0) = h;
    } else {
      for (size_t i = i0; i < total; ++i) A16[i] = (fp16)x[i];
    }
  } else {
    const int i = (b - 1280 - xb) * 256 + t;
    if (i < N) counts[i] = 1;  // self-loop
  }
}

// ---------------- CSR build ----------------
__global__ void k_count(const int* __restrict__ ei, int* counts, int E) {
  int i = blockIdx.x * 256 + threadIdx.x;
  if (i < E) atomicAdd(&counts[ei[E + i]], 1);
}

__global__ __launch_bounds__(256) void k_scan1(const int* __restrict__ counts,
                                               int* __restrict__ row_start,
                                               int* __restrict__ bsums, int N) {
  __shared__ int s[256];
  const int t = threadIdx.x;
  const int idx = blockIdx.x * 1024 + t * 4;
  int a0 = (idx + 0 < N) ? counts[idx + 0] : 0;
  int a1 = (idx + 1 < N) ? counts[idx + 1] : 0;
  int a2 = (idx + 2 < N) ? counts[idx + 2] : 0;
  int a3 = (idx + 3 < N) ? counts[idx + 3] : 0;
  const int mysum = a0 + a1 + a2 + a3;
  s[t] = mysum;
  __syncthreads();
  for (int ofs = 1; ofs < 256; ofs <<= 1) {
    int v = (t >= ofs) ? s[t - ofs] : 0;
    __syncthreads();
    s[t] += v;
    __syncthreads();
  }
  int excl = s[t] - mysum;
  if (idx + 0 < N) row_start[idx + 0] = excl;
  if (idx + 1 < N) row_start[idx + 1] = excl + a0;
  if (idx + 2 < N) row_start[idx + 2] = excl + a0 + a1;
  if (idx + 3 < N) row_start[idx + 3] = excl + a0 + a1 + a2;
  if (t == 255) bsums[blockIdx.x] = s[255];
}

__global__ void k_scan2(int* __restrict__ bsums, int* __restrict__ row_start, int nb, int N) {
  if (threadIdx.x == 0 && blockIdx.x == 0) {
    int run = 0;
    for (int i = 0; i < nb; ++i) {
      int v = bsums[i];
      bsums[i] = run;
      run += v;
    }
    row_start[N] = run;
  }
}

__global__ void k_scan3(int* __restrict__ row_start, int* __restrict__ cursor,
                        const int* __restrict__ bsums, int N) {
  int i = blockIdx.x * 256 + threadIdx.x;
  if (i < N) {
    int v = row_start[i] + bsums[i >> 10];
    row_start[i] = v;
    cursor[i] = v;
  }
}

__global__ void k_fill(const int* __restrict__ ei, int* cursor, int* __restrict__ csr_src,
                       int E, int N) {
  int i = blockIdx.x * 256 + threadIdx.x;
  if (i < E) {
    int s = ei[i], d = ei[E + i];
    int p = atomicAdd(&cursor[d], 1);
    csr_src[p] = s;
  } else if (i < E + N) {
    int n = i - E;
    int p = atomicAdd(&cursor[n], 1);
    csr_src[p] = n;
  }
}

// ---------------- fp16 MFMA GEMM (256-wide outputs, pair-swizzled grid) ----------------
// When asrcp != null: fused per-node attention scores als/ald [N,4].
// C16 path now supports bias (residual GEMM writes fp16 R16 + br).
__global__ __launch_bounds__(256) void k_gemm(
    const fp16* __restrict__ A16, const fp16* __restrict__ B16,
    const float* __restrict__ bias, float* __restrict__ Cf, fp16* __restrict__ C16,
    const float* __restrict__ asrcp, const float* __restrict__ adstp,
    float* __restrict__ alsp, float* __restrict__ aldp,
    int M, int ldc) {
  __shared__ fp16 Ash[128 * 32];
  __shared__ fp16 Bsh[128 * 32];
  const int nmb = (M + 127) >> 7;
  const int b = blockIdx.x;
  const int xcd = b & 7, q = b >> 3;
  const int jn = q & 1, pmb = (q >> 1) * 8 + xcd;
  if (pmb >= nmb) return;
  const int t = threadIdx.x;
  const int wave = t >> 6, lane = t & 63;
  const int m0 = pmb * 128, n0 = jn * 128;
  const int lrow = lane & 15, lq = lane >> 4;
  const int wm = (wave >> 1) * 64, wn = (wave & 1) * 64;

  f32x4 acc[4][4] = {};

  const int j0 = wave * 64 + lane, j1 = j0 + 256;
  const int ar0 = j0 >> 2, ar1 = j1 >> 2;
  const int ak0 = ((j0 & 3) ^ ((ar0 >> 1) & 3)) * 8;
  const int ak1 = ((j1 & 3) ^ ((ar1 >> 1) & 3)) * 8;
  const int gm0 = min(m0 + ar0, M - 1), gm1 = min(m0 + ar1, M - 1);
  const size_t oa0 = (size_t)gm0 * 256 + ak0, oa1 = (size_t)gm1 * 256 + ak1;
  const size_t ob0 = (size_t)(n0 + ar0) * 256 + ak0, ob1 = (size_t)(n0 + ar1) * 256 + ak1;
  const int l0 = wave * 512, l1 = 2048 + wave * 512;

  for (int k0 = 0; k0 < 256; k0 += 32) {
    __syncthreads();
    gld_lds16(A16 + oa0 + k0, Ash + l0);
    gld_lds16(A16 + oa1 + k0, Ash + l1);
    gld_lds16(B16 + ob0 + k0, Bsh + l0);
    gld_lds16(B16 + ob1 + k0, Bsh + l1);
    __syncthreads();
    half8 af[4], bf[4];
#pragma unroll
    for (int mi = 0; mi < 4; mi++) {
      int row = wm + mi * 16 + lrow;
      int off = row * 32 + ((lq ^ ((row >> 1) & 3)) << 3);
      af[mi] = *(const half8*)(Ash + off);
    }
#pragma unroll
    for (int ni = 0; ni < 4; ni++) {
      int row = wn + ni * 16 + lrow;
      int off = row * 32 + ((lq ^ ((row >> 1) & 3)) << 3);
      bf[ni] = *(const half8*)(Bsh + off);
    }
#pragma unroll
    for (int mi = 0; mi < 4; mi++)
#pragma unroll
      for (int ni = 0; ni < 4; ni++)
        acc[mi][ni] = __builtin_amdgcn_mfma_f32_16x16x32_f16(af[mi], bf[ni], acc[mi][ni], 0, 0, 0);
  }

#pragma unroll
  for (int mi = 0; mi < 4; mi++) {
    const int mb = m0 + wm + mi * 16 + lq * 4;
#pragma unroll
    for (int ni = 0; ni < 4; ni++) {
      const int n = n0 + wn + ni * 16 + lrow;
      const float bn = bias ? bias[n] : 0.f;
#pragma unroll
      for (int r = 0; r < 4; r++) {
        int m = mb + r;
        if (m < M) {
          if (C16) C16[(size_t)m * ldc + n] = (fp16)(acc[mi][ni][r] + bn);
          else     Cf[(size_t)m * ldc + n] = acc[mi][ni][r] + bn;
        }
      }
    }
  }

  // ---- fused attention-score epilogue (layer GEMMs only) ----
  if (asrcp) {
    const int headg = (n0 + wn) >> 6;
    float as4[4], ad4[4];
#pragma unroll
    for (int ni = 0; ni < 4; ni++) {
      int cg = n0 + wn + ni * 16 + lrow;
      as4[ni] = asrcp[cg];
      ad4[ni] = adstp[cg];
    }
#pragma unroll
    for (int mi = 0; mi < 4; mi++) {
      float ps[4] = {0.f, 0.f, 0.f, 0.f}, pd[4] = {0.f, 0.f, 0.f, 0.f};
#pragma unroll
      for (int ni = 0; ni < 4; ni++)
#pragma unroll
        for (int r = 0; r < 4; r++) {
          ps[r] += acc[mi][ni][r] * as4[ni];
          pd[r] += acc[mi][ni][r] * ad4[ni];
        }
#pragma unroll
      for (int o = 1; o < 16; o <<= 1)
#pragma unroll
        for (int r = 0; r < 4; r++) {
          ps[r] += __shfl_xor(ps[r], o, 64);
          pd[r] += __shfl_xor(pd[r], o, 64);
        }
      if (lrow == 0) {
#pragma unroll
        for (int r = 0; r < 4; r++) {
          int m = m0 + wm + mi * 16 + lq * 4 + r;
          if (m < M) {
            alsp[(size_t)m * 4 + headg] = ps[r];
            aldp[(size_t)m * 4 + headg] = pd[r];
          }
        }
      }
    }
  }
}

// ---------------- head GEMM with fused VAE finish ----------------
__global__ __launch_bounds__(256) void k_gemm_head(
    const fp16* __restrict__ A16, const fp16* __restrict__ B16,
    const float* __restrict__ bias_cat, const float* __restrict__ eps,
    const float* __restrict__ Wd, const float* __restrict__ bd,
    float* __restrict__ o_out, float* __restrict__ o_mu, float* __restrict__ o_lv,
    float* __restrict__ o_aux, int M) {
  __shared__ fp16 Ash[128 * 32];
  __shared__ fp16 Bsh[128 * 32];
  __shared__ float sZ[128][33];
  __shared__ float sWd[1024];
  const int t = threadIdx.x;
  const int wave = t >> 6, lane = t & 63;
  const int m0 = blockIdx.x * 128;
  const int lrow = lane & 15, lq = lane >> 4;
  const int wm = (wave >> 1) * 64, wn = (wave & 1) * 64;

  f32x4 acc[4][4] = {};

  const int j0 = wave * 64 + lane, j1 = j0 + 256;
  const int ar0 = j0 >> 2, ar1 = j1 >> 2;
  const int ak0 = ((j0 & 3) ^ ((ar0 >> 1) & 3)) * 8;
  const int ak1 = ((j1 & 3) ^ ((ar1 >> 1) & 3)) * 8;
  const int gm0 = min(m0 + ar0, M - 1), gm1 = min(m0 + ar1, M - 1);
  const size_t oa0 = (size_t)gm0 * 256 + ak0, oa1 = (size_t)gm1 * 256 + ak1;
  const size_t ob0 = (size_t)ar0 * 256 + ak0, ob1 = (size_t)ar1 * 256 + ak1;
  const int l0 = wave * 512, l1 = 2048 + wave * 512;

  for (int k0 = 0; k0 < 256; k0 += 32) {
    __syncthreads();
    gld_lds16(A16 + oa0 + k0, Ash + l0);
    gld_lds16(A16 + oa1 + k0, Ash + l1);
    gld_lds16(B16 + ob0 + k0, Bsh + l0);
    gld_lds16(B16 + ob1 + k0, Bsh + l1);
    __syncthreads();
    half8 af[4], bf[4];
#pragma unroll
    for (int mi = 0; mi < 4; mi++) {
      int row = wm + mi * 16 + lrow;
      int off = row * 32 + ((lq ^ ((row >> 1) & 3)) << 3);
      af[mi] = *(const half8*)(Ash + off);
    }
#pragma unroll
    for (int ni = 0; ni < 4; ni++) {
      int row = wn + ni * 16 + lrow;
      int off = row * 32 + ((lq ^ ((row >> 1) & 3)) << 3);
      bf[ni] = *(const half8*)(Bsh + off);
    }
#pragma unroll
    for (int mi = 0; mi < 4; mi++)
#pragma unroll
      for (int ni = 0; ni < 4; ni++)
        acc[mi][ni] = __builtin_amdgcn_mfma_f32_16x16x32_f16(af[mi], bf[ni], acc[mi][ni], 0, 0, 0);
  }

  for (int i = t; i < 1024; i += 256) sWd[i] = Wd[i];

  if ((wave & 1) == 0) {
#pragma unroll
    for (int mi = 0; mi < 4; mi++) {
      const int lrb = wm + mi * 16 + lq * 4;
      const int mb = m0 + lrb;
#pragma unroll
      for (int ni = 0; ni < 2; ni++) {
        const int jj = ni * 16 + lrow;
#pragma unroll
        for (int r = 0; r < 4; r++) {
          const int m = mb + r;
          if (m < M) {
            float mu = acc[mi][ni][r] + bias_cat[jj];
            float lv = acc[mi][ni + 2][r] + bias_cat[32 + jj];
            float z = mu + eps[(size_t)m * 32 + jj] * __expf(0.5f * lv);
            o_mu[(size_t)m * 32 + jj] = mu;
            o_lv[(size_t)m * 32 + jj] = lv;
            sZ[lrb + r][jj] = z;
          }
        }
      }
    }
  } else {
#pragma unroll
    for (int mi = 0; mi < 4; mi++) {
      const int mb = m0 + wm + mi * 16 + lq * 4;
#pragma unroll
      for (int ni = 0; ni < 4; ni++) {
        const int n = 64 + ni * 16 + lrow;
        if (n < 94) {
#pragma unroll
          for (int r = 0; r < 4; r++) {
            const int m = mb + r;
            if (m < M) o_aux[(size_t)m * 30 + (n - 64)] = acc[mi][ni][r] + bias_cat[n];
          }
        }
      }
    }
  }
  __syncthreads();
  const int jc = t & 31, rr = t >> 5;
#pragma unroll
  for (int it = 0; it < 16; ++it) {
    const int lr = it * 8 + rr;
    const int m = m0 + lr;
    if (m < M) {
      float o = bd[jc];
#pragma unroll
      for (int k = 0; k < 32; ++k) o += sZ[lr][k] * sWd[k * 32 + jc];
      o_out[(size_t)m * 32 + jc] = o;
    }
  }
}

// -------- single-pass segment softmax + weighted gather: 2 nodes/wave --------
// (Round-5 verified structure: 65 us/dispatch — best of 3 measured variants.)
__global__ __launch_bounds__(256) void k_gather(
    const fp16* __restrict__ h16, const float* __restrict__ als, const float* __restrict__ ald,
    const int* __restrict__ row_start, const int* __restrict__ csr_src,
    const float* __restrict__ bias, fp16* __restrict__ out, float* __restrict__ stats, int N) {
  if (blockIdx.x == 0) { stats[threadIdx.x] = 0.f; stats[256 + threadIdx.x] = 0.f; }
  const int wave = threadIdx.x >> 6, lane = threadIdx.x & 63;
  const int half = lane >> 5, l32 = lane & 31;
  const int n = blockIdx.x * 8 + wave * 2 + half;
  if (n >= N) return;
  const int head = l32 >> 3;
  const int c0 = l32 * 8;
  const float adh = ald[(size_t)n * 4 + head];
  const int beg = row_start[n], end = row_start[n + 1];
  float s = 0.f;
  float acc[8] = {0.f, 0.f, 0.f, 0.f, 0.f, 0.f, 0.f, 0.f};
#pragma unroll 4
  for (int i = beg; i < end; ++i) {
    const int sidx = csr_src[i];
    float e = als[(size_t)sidx * 4 + head] + adh;
    e = e > 0.f ? e : NEG_SLOPE * e;
    const float w = __expf(e);
    s += w;
    const half8 hv = *(const half8*)(h16 + (size_t)sidx * 256 + c0);
#pragma unroll
    for (int k = 0; k < 8; ++k) acc[k] += w * (float)hv[k];
  }
  const float inv = 1.f / (s + 1e-16f);
  const float4 b1 = *(const float4*)(bias + c0);
  const float4 b2 = *(const float4*)(bias + c0 + 4);
  half8 o;
  o[0] = (fp16)(acc[0] * inv + b1.x); o[1] = (fp16)(acc[1] * inv + b1.y);
  o[2] = (fp16)(acc[2] * inv + b1.z); o[3] = (fp16)(acc[3] * inv + b1.w);
  o[4] = (fp16)(acc[4] * inv + b2.x); o[5] = (fp16)(acc[5] * inv + b2.y);
  o[6] = (fp16)(acc[6] * inv + b2.z); o[7] = (fp16)(acc[7] * inv + b2.w);
  *(half8*)(out + (size_t)n * 256 + c0) = o;
}

// ---------------- batch norm stats (vectorized half4, LDS reduce) ----------------
// thread = (channel-quad, row-group): quad = t&63 (ch 4q..4q+3), rg = t>>6 (4x32 rows).
// Wave = 64 lanes covering 256 consecutive fp16 of one row -> 512B coalesced.
__global__ __launch_bounds__(256) void k_bn_stats(const fp16* __restrict__ x,
                                                  float* __restrict__ stats, int N) {
  __shared__ float sm[256], sq[256];
  const int t = threadIdx.x;
  sm[t] = 0.f; sq[t] = 0.f;
  __syncthreads();
  const int quad = t & 63, rg = t >> 6;
  const int c0 = quad * 4;
  const int r0 = blockIdx.x * 128 + rg * 32;
  float s0 = 0.f, s1 = 0.f, s2 = 0.f, s3 = 0.f;
  float q0 = 0.f, q1 = 0.f, q2 = 0.f, q3 = 0.f;
  const int rend = min(r0 + 32, N);
  for (int r = r0; r < rend; ++r) {
    const half4 hv = *(const half4*)(x + (size_t)r * 256 + c0);
    const float v0 = (float)hv[0], v1 = (float)hv[1], v2 = (float)hv[2], v3 = (float)hv[3];
    s0 += v0; q0 += v0 * v0;
    s1 += v1; q1 += v1 * v1;
    s2 += v2; q2 += v2 * v2;
    s3 += v3; q3 += v3 * v3;
  }
  atomicAdd(&sm[c0 + 0], s0); atomicAdd(&sq[c0 + 0], q0);
  atomicAdd(&sm[c0 + 1], s1); atomicAdd(&sq[c0 + 1], q1);
  atomicAdd(&sm[c0 + 2], s2); atomicAdd(&sq[c0 + 2], q2);
  atomicAdd(&sm[c0 + 3], s3); atomicAdd(&sq[c0 + 3], q3);
  __syncthreads();
  atomicAdd(&stats[t], sm[t]);
  atomicAdd(&stats[256 + t], sq[t]);
}

// ---------------- batch norm apply (vectorized half8, per-thread channel octet) ----------
// thread = (channel-octet o = t&31, row-group rg = t>>5); sc/sh computed once in regs.
// l<2: act16 = relu(bn(x)). l==2: enc = relu(bn(x)) + fp16 residual R16; write o_enc
// fp32 once (no read-modify-write) and act16 for the head GEMM.
__global__ __launch_bounds__(256) void k_bn_apply(
    const fp16* __restrict__ x, const float* __restrict__ stats,
    const float* __restrict__ g, const float* __restrict__ be,
    fp16* __restrict__ act16, const fp16* __restrict__ resid, float* __restrict__ enc_out,
    float invN, int N) {
  const int t = threadIdx.x;
  const int o = t & 31, rg = t >> 5;
  const int c0 = o * 8;
  float sc[8], sh[8];
#pragma unroll
  for (int k = 0; k < 8; ++k) {
    const int c = c0 + k;
    const float mu = stats[c] * invN;
    const float var = stats[256 + c] * invN - mu * mu;
    const float s = rsqrtf(var + BN_EPS) * g[c];
    sc[k] = s;
    sh[k] = be[c] - mu * s;
  }
  const int r0 = blockIdx.x * 128 + rg * 16;
  const int rend = min(r0 + 16, N);
  for (int r = r0; r < rend; ++r) {
    const size_t off = (size_t)r * 256 + c0;
    const half8 xv = *(const half8*)(x + off);
    float v[8];
#pragma unroll
    for (int k = 0; k < 8; ++k) {
      float u = (float)xv[k] * sc[k] + sh[k];
      v[k] = fmaxf(u, 0.f);
    }
    if (resid) {
      const half8 rv = *(const half8*)(resid + off);
#pragma unroll
      for (int k = 0; k < 8; ++k) v[k] += (float)rv[k];
      float4 e1, e2;
      e1.x = v[0]; e1.y = v[1]; e1.z = v[2]; e1.w = v[3];
      e2.x = v[4]; e2.y = v[5]; e2.z = v[6]; e2.w = v[7];
      *(float4*)(enc_out + off) = e1;
      *(float4*)(enc_out + off + 4) = e2;
    }
    half8 av;
#pragma unroll
    for (int k = 0; k < 8; ++k) av[k] = (fp16)v[k];
    *(half8*)(act16 + off) = av;
  }
}

// ---------------- launcher ----------------
extern "C" void kernel_launch(void* const* d_in, const int* in_sizes, int n_in,
                              void* d_out, int out_size, void* d_ws, size_t ws_size,
                              hipStream_t stream) {
  const float* x   = (const float*)d_in[0];
  const int*   ei  = (const int*)d_in[1];
  const float* eps = (const float*)d_in[2];
  const float* Wg[3]   = {(const float*)d_in[3], (const float*)d_in[9],  (const float*)d_in[15]};
  const float* asrc[3] = {(const float*)d_in[4], (const float*)d_in[10], (const float*)d_in[16]};
  const float* adst[3] = {(const float*)d_in[5], (const float*)d_in[11], (const float*)d_in[17]};
  const float* bg[3]   = {(const float*)d_in[6], (const float*)d_in[12], (const float*)d_in[18]};
  const float* gam[3]  = {(const float*)d_in[7], (const float*)d_in[13], (const float*)d_in[19]};
  const float* bet[3]  = {(const float*)d_in[8], (const float*)d_in[14], (const float*)d_in[20]};
  const float* Wr  = (const float*)d_in[21];
  const float* br  = (const float*)d_in[22];
  const float* Wmu = (const float*)d_in[23];
  const float* bmu = (const float*)d_in[24];
  const float* Wlv = (const float*)d_in[25];
  const float* blv = (const float*)d_in[26];
  const float* Wd  = (const float*)d_in[27];
  const float* bd  = (const float*)d_in[28];
  const float* Wa  = (const float*)d_in[29];
  const float* ba  = (const float*)d_in[30];

  const int N = in_sizes[0] / 256;
  const int E = in_sizes[1] / 2;

  float* outp  = (float*)d_out;
  float* o_out = outp;
  float* o_mu  = outp + (size_t)N * 32;
  float* o_lv  = outp + (size_t)N * 64;
  float* o_aux = outp + (size_t)N * 96;
  float* o_enc = outp + (size_t)N * 96 + (size_t)N * 30;

  char* p = (char*)d_ws;
  auto carve = [&](size_t bytes) -> char* {
    char* r = p;
    p += (bytes + 255) & ~(size_t)255;
    return r;
  };
  int* counts    = (int*)carve((size_t)N * 4);
  int* row_start = (int*)carve(((size_t)N + 1) * 4);
  int* cursor    = (int*)carve((size_t)N * 4);
  int* csr_src   = (int*)carve((size_t)(E + N) * 4);
  int* bsums     = (int*)carve(((size_t)N / 1024 + 2) * 4);
  fp16* Wt16[4];
  for (int i = 0; i < 4; ++i) Wt16[i] = (fp16*)carve(256 * 256 * 2);
  fp16* Wh16 = (fp16*)carve(128 * 256 * 2);
  float* bias_cat = (float*)carve(128 * 4);
  fp16* A16 = (fp16*)carve((size_t)N * 256 * 2);    // activations fp16
  fp16* H16 = (fp16*)carve((size_t)N * 256 * 2);    // h in fp16 for gather
  fp16* R16 = (fp16*)carve((size_t)N * 256 * 2);    // residual fp16
  fp16* AGG16 = (fp16*)carve((size_t)N * 256 * 2);  // GAT layer output (fp16)
  float* als = (float*)carve((size_t)N * 4 * 4);
  float* ald = (float*)carve((size_t)N * 4 * 4);
  float* stats = (float*)carve(512 * 4);

  dim3 b256(256);

  // fused prep: 4 W transposes + head W + x->fp16 (vectorized) + counts init
  const int xb = ((int)((size_t)N * 256 + 1023)) / 1024;
  const int cb = (N + 255) / 256;
  k_prep<<<1280 + xb + cb, b256, 0, stream>>>(
      Wr, Wg[0], Wg[1], Wg[2], Wt16[0], Wt16[1], Wt16[2], Wt16[3],
      Wmu, bmu, Wlv, blv, Wa, ba, Wh16, bias_cat, x, A16, counts, N, xb);

  // CSR by dst (self-loops included via counts init = 1)
  const int nb_scan = (N + 1023) / 1024;
  k_count<<<(E + 255) / 256, b256, 0, stream>>>(ei, counts, E);
  k_scan1<<<nb_scan, b256, 0, stream>>>(counts, row_start, bsums, N);
  k_scan2<<<1, 64, 0, stream>>>(bsums, row_start, nb_scan, N);
  k_scan3<<<(N + 255) / 256, b256, 0, stream>>>(row_start, cursor, bsums, N);
  k_fill<<<(E + N + 255) / 256, b256, 0, stream>>>(ei, cursor, csr_src, E, N);

  // pair-swizzled 1D grid for 256-wide GEMMs
  const int nmb = (N + 127) / 128;
  const int g1d = 8 * ((nmb + 7) / 8) * 2;
  // residual = x @ Wr + br -> fp16 R16 (bn_apply l==2 adds + writes o_enc once)
  k_gemm<<<g1d, b256, 0, stream>>>(A16, Wt16[0], br, nullptr, R16,
                                   nullptr, nullptr, nullptr, nullptr, N, 256);

  const float invN = 1.0f / (float)N;
  const int bnb = (N + 127) / 128;
  for (int l = 0; l < 3; ++l) {
    // GEMM + fused als/ald epilogue
    k_gemm<<<g1d, b256, 0, stream>>>(A16, Wt16[l + 1], nullptr, nullptr, H16,
                                     asrc[l], adst[l], als, ald, N, 256);
    k_gather<<<(N + 7) / 8, b256, 0, stream>>>(H16, als, ald, row_start, csr_src, bg[l],
                                               AGG16, stats, N);
    k_bn_stats<<<bnb, b256, 0, stream>>>(AGG16, stats, N);
    if (l < 2)
      k_bn_apply<<<bnb, b256, 0, stream>>>(AGG16, stats, gam[l], bet[l], A16,
                                           nullptr, nullptr, invN, N);
    else
      k_bn_apply<<<bnb, b256, 0, stream>>>(AGG16, stats, gam[l], bet[l], A16,
                                           R16, o_enc, invN, N);
  }

  // head GEMM with fused VAE finish (no FHEAD, no k_finish)
  k_gemm_head<<<nmb, b256, 0, stream>>>(A16, Wh16, bias_cat, eps, Wd, bd,
                                        o_out, o_mu, o_lv, o_aux, N);
}